// Round 1
// baseline (709.884 us; speedup 1.0000x reference)
//
#include <hip/hip_runtime.h>
#include <hip/hip_bf16.h>

#define N_NODES 131072
#define B_GRAPHS 256
#define NPG 512
#define KNN 7
#define HEADS 4

// ---------------------------------------------------------------------------
// Kernel 1: per-graph brute-force kNN (K=7) over 3D positions.
// One block per graph (512 threads). Positions staged in LDS. Each thread
// keeps a sorted top-7 in registers (fully unrolled -> no scratch).
// ---------------------------------------------------------------------------
__global__ __launch_bounds__(512) void knn_kernel(const float* __restrict__ pos,
                                                  int* __restrict__ knn) {
    __shared__ float px[NPG], py[NPG], pz[NPG];
    const int g = blockIdx.x;
    const int t = threadIdx.x;
    const float* p = pos + (size_t)g * NPG * 3;
    px[t] = p[t * 3 + 0];
    py[t] = p[t * 3 + 1];
    pz[t] = p[t * 3 + 2];
    __syncthreads();

    const float mx = px[t], my = py[t], mz = pz[t];
    float b0 = 1e30f, b1 = 1e30f, b2 = 1e30f, b3 = 1e30f, b4 = 1e30f, b5 = 1e30f, b6 = 1e30f;
    int   n0 = 0, n1 = 0, n2 = 0, n3 = 0, n4 = 0, n5 = 0, n6 = 0;

    for (int j = 0; j < NPG; ++j) {
        if (j == t) continue;  // no self-loops (ref adds 1e10 on diagonal)
        const float dx = mx - px[j];
        const float dy = my - py[j];
        const float dz = mz - pz[j];
        const float d2 = dx * dx + dy * dy + dz * dz;
        if (d2 < b6) {
            b6 = d2; n6 = j;
#define CSWAP(da, ia, db, ib) \
            if (db < da) { float _t = da; da = db; db = _t; int _i = ia; ia = ib; ib = _i; }
            CSWAP(b5, n5, b6, n6)
            CSWAP(b4, n4, b5, n5)
            CSWAP(b3, n3, b4, n4)
            CSWAP(b2, n2, b3, n3)
            CSWAP(b1, n1, b2, n2)
            CSWAP(b0, n0, b1, n1)
#undef CSWAP
        }
    }
    const int base = (g * NPG + t) * KNN;
    const int off = g * NPG;
    knn[base + 0] = off + n0;
    knn[base + 1] = off + n1;
    knn[base + 2] = off + n2;
    knn[base + 3] = off + n3;
    knn[base + 4] = off + n4;
    knn[base + 5] = off + n5;
    knn[base + 6] = off + n6;
}

// ---------------------------------------------------------------------------
// Kernel 2: xl1 = x @ Wl1 + bl1   ([N,10] @ [10,64])
// One thread per output element. W loads coalesced, x loads broadcast.
// ---------------------------------------------------------------------------
__global__ __launch_bounds__(256) void lin1_kernel(const float* __restrict__ x,
                                                   const float* __restrict__ W,
                                                   const float* __restrict__ b,
                                                   float* __restrict__ out) {
    const int idx = blockIdx.x * 256 + threadIdx.x;   // N*64 total
    const int ch = idx & 63;
    const size_t node = (size_t)(idx >> 6);
    const float* xrow = x + node * 10;
    float acc = b[ch];
#pragma unroll
    for (int k = 0; k < 10; ++k) acc += xrow[k] * W[k * 64 + ch];
    out[node * 64 + ch] = acc;
}

// ---------------------------------------------------------------------------
// Kernel 3: GATv2 layer-1 aggregation. One wave (64 lanes) per node; lane =
// channel (H=4, C=16). xr computed on the fly (10 MACs). Head-wise alpha via
// 16-lane shfl_xor reduce. Softmax over the 7 neighbors in registers.
// ---------------------------------------------------------------------------
__global__ __launch_bounds__(256) void agg1_kernel(const float* __restrict__ x,
                                                   const float* __restrict__ xl,
                                                   const int* __restrict__ knn,
                                                   const float* __restrict__ Wr,
                                                   const float* __restrict__ br,
                                                   const float* __restrict__ att,
                                                   const float* __restrict__ bias,
                                                   float* __restrict__ out) {
    const int tid = threadIdx.x;
    const int lane = tid & 63;
    const size_t node = (size_t)blockIdx.x * 4 + (tid >> 6);

    // xr[node][lane] = br[lane] + sum_k x[node][k] * Wr[k][lane]
    const float* xrow = x + node * 10;
    float xr = br[lane];
#pragma unroll
    for (int k = 0; k < 10; ++k) xr += xrow[k] * Wr[k * 64 + lane];

    const float attv = att[lane];  // att[h][c] flat == lane (h=lane>>4, c=lane&15)
    const int* nb = knn + node * KNN;

    float xlj[KNN], alpha[KNN];
#pragma unroll
    for (int k = 0; k < KNN; ++k) {
        const int j = nb[k];
        const float v = xl[(size_t)j * 64 + lane];
        xlj[k] = v;
        float m = v + xr;
        m = m > 0.f ? m : 0.2f * m;          // leaky_relu(., 0.2)
        float psum = m * attv;
        psum += __shfl_xor(psum, 1);
        psum += __shfl_xor(psum, 2);
        psum += __shfl_xor(psum, 4);
        psum += __shfl_xor(psum, 8);         // reduce over C=16 lanes
        alpha[k] = psum;
    }
    float amax = alpha[0];
#pragma unroll
    for (int k = 1; k < KNN; ++k) amax = fmaxf(amax, alpha[k]);
    float denom = 0.f, acc = 0.f;
#pragma unroll
    for (int k = 0; k < KNN; ++k) {
        const float e = expf(alpha[k] - amax);
        denom += e;
        acc += e * xlj[k];
    }
    out[node * 64 + lane] = acc / denom + bias[lane];
}

// ---------------------------------------------------------------------------
// Kernel 4: xl2 = h1 @ Wl2 + bl2   ([N,64] @ [64,128])
// ---------------------------------------------------------------------------
__global__ __launch_bounds__(256) void lin2_kernel(const float* __restrict__ h,
                                                   const float* __restrict__ W,
                                                   const float* __restrict__ b,
                                                   float* __restrict__ out) {
    const int idx = blockIdx.x * 256 + threadIdx.x;   // N*128 total
    const int ch = idx & 127;
    const size_t node = (size_t)(idx >> 7);
    const float* hrow = h + node * 64;
    float acc = b[ch];
#pragma unroll
    for (int k = 0; k < 64; ++k) acc += hrow[k] * W[k * 128 + ch];
    out[node * 128 + ch] = acc;
}

// ---------------------------------------------------------------------------
// Kernel 5: GATv2 layer-2 aggregation. 128 threads per node (2 nodes/block);
// ch = tid&127, head group = 32 contiguous lanes (within one wave half).
// ---------------------------------------------------------------------------
__global__ __launch_bounds__(256) void agg2_kernel(const float* __restrict__ h1,
                                                   const float* __restrict__ xl,
                                                   const int* __restrict__ knn,
                                                   const float* __restrict__ Wr,
                                                   const float* __restrict__ br,
                                                   const float* __restrict__ att,
                                                   const float* __restrict__ bias,
                                                   float* __restrict__ out) {
    const int tid = threadIdx.x;
    const int ch = tid & 127;
    const size_t node = (size_t)blockIdx.x * 2 + (tid >> 7);

    const float* hrow = h1 + node * 64;
    float xr = br[ch];
#pragma unroll
    for (int k = 0; k < 64; ++k) xr += hrow[k] * Wr[k * 128 + ch];

    const float attv = att[ch];  // att[h][c] flat == ch (h=ch>>5, c=ch&31)
    const int* nb = knn + node * KNN;

    float xlj[KNN], alpha[KNN];
#pragma unroll
    for (int k = 0; k < KNN; ++k) {
        const int j = nb[k];
        const float v = xl[(size_t)j * 128 + ch];
        xlj[k] = v;
        float m = v + xr;
        m = m > 0.f ? m : 0.2f * m;
        float psum = m * attv;
        psum += __shfl_xor(psum, 1);
        psum += __shfl_xor(psum, 2);
        psum += __shfl_xor(psum, 4);
        psum += __shfl_xor(psum, 8);
        psum += __shfl_xor(psum, 16);        // reduce over C=32 lanes
        alpha[k] = psum;
    }
    float amax = alpha[0];
#pragma unroll
    for (int k = 1; k < KNN; ++k) amax = fmaxf(amax, alpha[k]);
    float denom = 0.f, acc = 0.f;
#pragma unroll
    for (int k = 0; k < KNN; ++k) {
        const float e = expf(alpha[k] - amax);
        denom += e;
        acc += e * xlj[k];
    }
    out[node * 128 + ch] = acc / denom + bias[ch];
}

// ---------------------------------------------------------------------------
// Kernel 6: per-graph mean pool. One block per graph; 4 partial slices of 128
// nodes each, combined through LDS.
// ---------------------------------------------------------------------------
__global__ __launch_bounds__(512) void pool_kernel(const float* __restrict__ h2,
                                                   float* __restrict__ out) {
    __shared__ float partial[512];
    const int g = blockIdx.x;
    const int t = threadIdx.x;
    const int c = t & 127;
    const int sl = t >> 7;                     // slice 0..3
    const float* base = h2 + ((size_t)g * NPG + sl * 128) * 128;
    float s = 0.f;
    for (int n = 0; n < 128; ++n) s += base[(size_t)n * 128 + c];
    partial[t] = s;
    __syncthreads();
    if (t < 128) {
        const float r = partial[t] + partial[t + 128] + partial[t + 256] + partial[t + 384];
        out[g * 128 + t] = r * (1.f / 512.f);
    }
}

extern "C" void kernel_launch(void* const* d_in, const int* in_sizes, int n_in,
                              void* d_out, int out_size, void* d_ws, size_t ws_size,
                              hipStream_t stream) {
    const float* pos   = (const float*)d_in[0];
    const float* x     = (const float*)d_in[1];
    // d_in[2] = batch (implicit: nodes ordered by graph, NPG each) -- unused
    const float* Wl1   = (const float*)d_in[3];
    const float* bl1   = (const float*)d_in[4];
    const float* Wr1   = (const float*)d_in[5];
    const float* br1   = (const float*)d_in[6];
    const float* att1  = (const float*)d_in[7];
    const float* bias1 = (const float*)d_in[8];
    const float* Wl2   = (const float*)d_in[9];
    const float* bl2   = (const float*)d_in[10];
    const float* Wr2   = (const float*)d_in[11];
    const float* br2   = (const float*)d_in[12];
    const float* att2  = (const float*)d_in[13];
    const float* bias2 = (const float*)d_in[14];
    float* out = (float*)d_out;

    // Workspace layout (liveness-overlapped):
    //   [0,       3.67MB)  knn indices  [N][7] int32
    //   [3.67MB,  37.2MB)  h1   [N][64]
    //   [37.2MB, 104.3MB)  xl2  [N][128]
    //   [104.3MB,171.4MB)  slot: xl1 [N][64] (dies after agg1), then h2 [N][128]
    char* ws = (char*)d_ws;
    int*   knn  = (int*)(ws + 0);
    float* h1   = (float*)(ws + 3670016);
    float* xl2  = (float*)(ws + 37224448);
    float* slot = (float*)(ws + 104333312);
    float* xl1  = slot;
    float* h2   = slot;

    knn_kernel<<<B_GRAPHS, NPG, 0, stream>>>(pos, knn);
    lin1_kernel<<<(N_NODES * 64) / 256, 256, 0, stream>>>(x, Wl1, bl1, xl1);
    agg1_kernel<<<N_NODES / 4, 256, 0, stream>>>(x, xl1, knn, Wr1, br1, att1, bias1, h1);
    lin2_kernel<<<(N_NODES * 128) / 256, 256, 0, stream>>>(h1, Wl2, bl2, xl2);
    agg2_kernel<<<N_NODES / 2, 256, 0, stream>>>(h1, xl2, knn, Wr2, br2, att2, bias2, h2);
    pool_kernel<<<B_GRAPHS, NPG, 0, stream>>>(h2, out);
}

// Round 2
// 551.874 us; speedup vs baseline: 1.2863x; 1.2863x over previous
//
#include <hip/hip_runtime.h>
#include <hip/hip_bf16.h>

#define N_NODES 131072
#define B_GRAPHS 256
#define NPG 512
#define KNN 7
#define HEADS 4

using f4 = __attribute__((ext_vector_type(4))) float;

// ---------------------------------------------------------------------------
// Kernel 1: per-graph brute-force kNN (K=7) over 3D positions.
// One block per graph (512 threads). Positions staged in LDS. Each thread
// keeps a sorted top-7 in registers (fully unrolled -> no scratch).
// ---------------------------------------------------------------------------
__global__ __launch_bounds__(512) void knn_kernel(const float* __restrict__ pos,
                                                  int* __restrict__ knn) {
    __shared__ float px[NPG], py[NPG], pz[NPG];
    const int g = blockIdx.x;
    const int t = threadIdx.x;
    const float* p = pos + (size_t)g * NPG * 3;
    px[t] = p[t * 3 + 0];
    py[t] = p[t * 3 + 1];
    pz[t] = p[t * 3 + 2];
    __syncthreads();

    const float mx = px[t], my = py[t], mz = pz[t];
    float b0 = 1e30f, b1 = 1e30f, b2 = 1e30f, b3 = 1e30f, b4 = 1e30f, b5 = 1e30f, b6 = 1e30f;
    int   n0 = 0, n1 = 0, n2 = 0, n3 = 0, n4 = 0, n5 = 0, n6 = 0;

    for (int j = 0; j < NPG; ++j) {
        if (j == t) continue;  // no self-loops (ref adds 1e10 on diagonal)
        const float dx = mx - px[j];
        const float dy = my - py[j];
        const float dz = mz - pz[j];
        const float d2 = dx * dx + dy * dy + dz * dz;
        if (d2 < b6) {
            b6 = d2; n6 = j;
#define CSWAP(da, ia, db, ib) \
            if (db < da) { float _t = da; da = db; db = _t; int _i = ia; ia = ib; ib = _i; }
            CSWAP(b5, n5, b6, n6)
            CSWAP(b4, n4, b5, n5)
            CSWAP(b3, n3, b4, n4)
            CSWAP(b2, n2, b3, n3)
            CSWAP(b1, n1, b2, n2)
            CSWAP(b0, n0, b1, n1)
#undef CSWAP
        }
    }
    const int base = (g * NPG + t) * KNN;
    const int off = g * NPG;
    knn[base + 0] = off + n0;
    knn[base + 1] = off + n1;
    knn[base + 2] = off + n2;
    knn[base + 3] = off + n3;
    knn[base + 4] = off + n4;
    knn[base + 5] = off + n5;
    knn[base + 6] = off + n6;
}

// ---------------------------------------------------------------------------
// Kernel 2: fused xl1 = x@Wl1+bl1, xr1 = x@Wr1+br1  ([N,10]@[10,64]).
// One thread per (node, ch4): float4 accumulators for both outputs.
// ---------------------------------------------------------------------------
__global__ __launch_bounds__(256) void lin1_kernel(const float* __restrict__ x,
                                                   const float* __restrict__ Wl,
                                                   const float* __restrict__ bl,
                                                   const float* __restrict__ Wr,
                                                   const float* __restrict__ br,
                                                   float* __restrict__ xl1,
                                                   float* __restrict__ xr1) {
    const int idx = blockIdx.x * 256 + threadIdx.x;   // N*16
    const int c4 = idx & 15;
    const size_t node = (size_t)(idx >> 4);
    const float* xrow = x + node * 10;
    f4 al = ((const f4*)bl)[c4];
    f4 ar = ((const f4*)br)[c4];
#pragma unroll
    for (int k = 0; k < 10; ++k) {
        const float xv = xrow[k];
        al += xv * ((const f4*)(Wl + k * 64))[c4];
        ar += xv * ((const f4*)(Wr + k * 64))[c4];
    }
    ((f4*)(xl1 + node * 64))[c4] = al;
    ((f4*)(xr1 + node * 64))[c4] = ar;
}

// ---------------------------------------------------------------------------
// Kernel 3: GATv2 layer-1 aggregation. One thread per (node, head), C=16.
// Two-pass over the 7 neighbors: pass1 alpha (in-thread dot, no shuffles),
// pass2 weighted sum (reloads hit L1/L2).
// ---------------------------------------------------------------------------
__global__ __launch_bounds__(256) void agg1_kernel(const float* __restrict__ xl,
                                                   const float* __restrict__ xr,
                                                   const int* __restrict__ knn,
                                                   const float* __restrict__ att,
                                                   const float* __restrict__ bias,
                                                   float* __restrict__ out) {
    const int idx = blockIdx.x * 256 + threadIdx.x;   // N*4
    const int h = idx & 3;
    const size_t node = (size_t)(idx >> 2);
    const int* nb = knn + node * KNN;
    int j[KNN];
#pragma unroll
    for (int k = 0; k < KNN; ++k) j[k] = nb[k];

    f4 xr4[4], at4[4];
    const f4* xrp = (const f4*)(xr + node * 64 + h * 16);
    const f4* atp = (const f4*)(att + h * 16);
#pragma unroll
    for (int i = 0; i < 4; ++i) { xr4[i] = xrp[i]; at4[i] = atp[i]; }

    float alpha[KNN];
#pragma unroll
    for (int k = 0; k < KNN; ++k) {
        const f4* xlp = (const f4*)(xl + (size_t)j[k] * 64 + h * 16);
        float s = 0.f;
#pragma unroll
        for (int i = 0; i < 4; ++i) {
            const f4 m = xlp[i] + xr4[i];
#pragma unroll
            for (int c = 0; c < 4; ++c) {
                float mm = m[c];
                mm = mm > 0.f ? mm : 0.2f * mm;   // leaky_relu(., 0.2)
                s += mm * at4[i][c];
            }
        }
        alpha[k] = s;
    }
    float amax = alpha[0];
#pragma unroll
    for (int k = 1; k < KNN; ++k) amax = fmaxf(amax, alpha[k]);
    float e[KNN];
    float denom = 0.f;
#pragma unroll
    for (int k = 0; k < KNN; ++k) { e[k] = expf(alpha[k] - amax); denom += e[k]; }
    const float rd = 1.f / denom;

    f4 o4[4];
#pragma unroll
    for (int i = 0; i < 4; ++i) o4[i] = 0.f;
#pragma unroll
    for (int k = 0; k < KNN; ++k) {
        const f4* xlp = (const f4*)(xl + (size_t)j[k] * 64 + h * 16);
#pragma unroll
        for (int i = 0; i < 4; ++i) o4[i] += e[k] * xlp[i];
    }
    const f4* bp = (const f4*)(bias + h * 16);
    f4* op = (f4*)(out + node * 64 + h * 16);
#pragma unroll
    for (int i = 0; i < 4; ++i) op[i] = o4[i] * rd + bp[i];
}

// ---------------------------------------------------------------------------
// Kernel 4: fused xl2 = h1@Wl2+bl2, xr2 = h1@Wr2+br2  ([N,64]@[64,128]).
// ---------------------------------------------------------------------------
__global__ __launch_bounds__(256) void lin2_kernel(const float* __restrict__ h,
                                                   const float* __restrict__ Wl,
                                                   const float* __restrict__ bl,
                                                   const float* __restrict__ Wr,
                                                   const float* __restrict__ br,
                                                   float* __restrict__ xl2,
                                                   float* __restrict__ xr2) {
    const int idx = blockIdx.x * 256 + threadIdx.x;   // N*32
    const int c4 = idx & 31;
    const size_t node = (size_t)(idx >> 5);
    const float* hrow = h + node * 64;
    f4 al = ((const f4*)bl)[c4];
    f4 ar = ((const f4*)br)[c4];
#pragma unroll 8
    for (int k = 0; k < 64; ++k) {
        const float hv = hrow[k];
        al += hv * ((const f4*)(Wl + k * 128))[c4];
        ar += hv * ((const f4*)(Wr + k * 128))[c4];
    }
    ((f4*)(xl2 + node * 128))[c4] = al;
    ((f4*)(xr2 + node * 128))[c4] = ar;
}

// ---------------------------------------------------------------------------
// Kernel 5: GATv2 layer-2 aggregation fused with block-level mean pooling.
// One thread per (node, head), C=32. Block = 256 threads = 64 nodes (all in
// one graph: 8 blocks per graph). Per-node outputs go to LDS, reduced
// deterministically to per-block partial sums (bias added in stage 2).
// ---------------------------------------------------------------------------
__global__ __launch_bounds__(256) void agg2_pool_kernel(const float* __restrict__ xl,
                                                        const float* __restrict__ xr,
                                                        const int* __restrict__ knn,
                                                        const float* __restrict__ att,
                                                        float* __restrict__ partial) {
    __shared__ float sm[64 * 128];
    const int tid = threadIdx.x;
    const int h = tid & 3;
    const int n64 = tid >> 2;
    const size_t node = (size_t)blockIdx.x * 64 + n64;
    const int* nb = knn + node * KNN;
    int j[KNN];
#pragma unroll
    for (int k = 0; k < KNN; ++k) j[k] = nb[k];

    f4 xr4[8], at4[8];
    const f4* xrp = (const f4*)(xr + node * 128 + h * 32);
    const f4* atp = (const f4*)(att + h * 32);
#pragma unroll
    for (int i = 0; i < 8; ++i) { xr4[i] = xrp[i]; at4[i] = atp[i]; }

    float alpha[KNN];
#pragma unroll
    for (int k = 0; k < KNN; ++k) {
        const f4* xlp = (const f4*)(xl + (size_t)j[k] * 128 + h * 32);
        float s = 0.f;
#pragma unroll
        for (int i = 0; i < 8; ++i) {
            const f4 m = xlp[i] + xr4[i];
#pragma unroll
            for (int c = 0; c < 4; ++c) {
                float mm = m[c];
                mm = mm > 0.f ? mm : 0.2f * mm;
                s += mm * at4[i][c];
            }
        }
        alpha[k] = s;
    }
    float amax = alpha[0];
#pragma unroll
    for (int k = 1; k < KNN; ++k) amax = fmaxf(amax, alpha[k]);
    float e[KNN];
    float denom = 0.f;
#pragma unroll
    for (int k = 0; k < KNN; ++k) { e[k] = expf(alpha[k] - amax); denom += e[k]; }
    const float rd = 1.f / denom;

    f4 o4[8];
#pragma unroll
    for (int i = 0; i < 8; ++i) o4[i] = 0.f;
#pragma unroll
    for (int k = 0; k < KNN; ++k) {
        const f4* xlp = (const f4*)(xl + (size_t)j[k] * 128 + h * 32);
#pragma unroll
        for (int i = 0; i < 8; ++i) o4[i] += e[k] * xlp[i];
    }

    // stage per-node result (x 1/denom, no bias) into LDS: sm[n64][h*32 + i]
    f4* smp = (f4*)sm;
#pragma unroll
    for (int i = 0; i < 8; ++i) smp[n64 * 32 + h * 8 + i] = o4[i] * rd;
    __syncthreads();

    // deterministic block reduce over the 64 nodes -> per-block partial [128]
    if (tid < 128) {
        float s = 0.f;
#pragma unroll 8
        for (int n = 0; n < 64; ++n) s += sm[n * 128 + tid];
        partial[(size_t)blockIdx.x * 128 + tid] = s;
    }
}

// ---------------------------------------------------------------------------
// Kernel 6: stage-2 pool. One block per graph; combines the 8 block partials,
// divides by NPG, adds bias2.
// ---------------------------------------------------------------------------
__global__ __launch_bounds__(128) void pool2_kernel(const float* __restrict__ partial,
                                                    const float* __restrict__ bias,
                                                    float* __restrict__ out) {
    const int g = blockIdx.x;
    const int c = threadIdx.x;
    float s = 0.f;
#pragma unroll
    for (int b = 0; b < 8; ++b) s += partial[(size_t)(g * 8 + b) * 128 + c];
    out[g * 128 + c] = s * (1.f / 512.f) + bias[c];
}

extern "C" void kernel_launch(void* const* d_in, const int* in_sizes, int n_in,
                              void* d_out, int out_size, void* d_ws, size_t ws_size,
                              hipStream_t stream) {
    const float* pos   = (const float*)d_in[0];
    const float* x     = (const float*)d_in[1];
    // d_in[2] = batch (implicit: nodes ordered by graph, NPG each) -- unused
    const float* Wl1   = (const float*)d_in[3];
    const float* bl1   = (const float*)d_in[4];
    const float* Wr1   = (const float*)d_in[5];
    const float* br1   = (const float*)d_in[6];
    const float* att1  = (const float*)d_in[7];
    const float* bias1 = (const float*)d_in[8];
    const float* Wl2   = (const float*)d_in[9];
    const float* bl2   = (const float*)d_in[10];
    const float* Wr2   = (const float*)d_in[11];
    const float* br2   = (const float*)d_in[12];
    const float* att2  = (const float*)d_in[13];
    const float* bias2 = (const float*)d_in[14];
    float* out = (float*)d_out;

    // Workspace layout (liveness-overlapped, total 171,442,176 B == round-1):
    //   [0,        3.67MB)  knn [N][7] int32                     (live: all)
    //   [3.67MB,  70.78MB)  slotA: xl1|xr1 [N][64]x2  -> xl2 [N][128]
    //   [70.78MB,104.33MB)  h1 [N][64]                -> partial [2048][128]
    //   [104.33, 171.44MB)  xr2 [N][128]
    char* ws = (char*)d_ws;
    int*   knn  = (int*)(ws + 0);
    float* xl1  = (float*)(ws + 3670016);
    float* xr1  = (float*)(ws + 37224448);
    float* h1   = (float*)(ws + 70778880);
    float* xl2  = (float*)(ws + 3670016);     // over dead xl1|xr1
    float* xr2  = (float*)(ws + 104333312);
    float* partial = (float*)(ws + 70778880); // over dead h1

    knn_kernel<<<B_GRAPHS, NPG, 0, stream>>>(pos, knn);
    lin1_kernel<<<(N_NODES * 16) / 256, 256, 0, stream>>>(x, Wl1, bl1, Wr1, br1, xl1, xr1);
    agg1_kernel<<<(N_NODES * 4) / 256, 256, 0, stream>>>(xl1, xr1, knn, att1, bias1, h1);
    lin2_kernel<<<(N_NODES * 32) / 256, 256, 0, stream>>>(h1, Wl2, bl2, Wr2, br2, xl2, xr2);
    agg2_pool_kernel<<<N_NODES / 64, 256, 0, stream>>>(xl2, xr2, knn, att2, partial);
    pool2_kernel<<<B_GRAPHS, 128, 0, stream>>>(partial, bias2, out);
}

// Round 3
// 362.076 us; speedup vs baseline: 1.9606x; 1.5242x over previous
//
#include <hip/hip_runtime.h>
#include <hip/hip_bf16.h>

#define N_NODES 131072
#define B_GRAPHS 256
#define NPG 512
#define KNN 7
#define HEADS 4

using f4 = __attribute__((ext_vector_type(4))) float;

// ---------------------------------------------------------------------------
// Kernel 1: per-graph brute-force kNN (K=7) over 3D positions.
// One block per graph (512 threads). Positions staged in LDS. Each thread
// keeps a sorted top-7 in registers (fully unrolled -> no scratch).
// ---------------------------------------------------------------------------
__global__ __launch_bounds__(512) void knn_kernel(const float* __restrict__ pos,
                                                  int* __restrict__ knn) {
    __shared__ float px[NPG], py[NPG], pz[NPG];
    const int g = blockIdx.x;
    const int t = threadIdx.x;
    const float* p = pos + (size_t)g * NPG * 3;
    px[t] = p[t * 3 + 0];
    py[t] = p[t * 3 + 1];
    pz[t] = p[t * 3 + 2];
    __syncthreads();

    const float mx = px[t], my = py[t], mz = pz[t];
    float b0 = 1e30f, b1 = 1e30f, b2 = 1e30f, b3 = 1e30f, b4 = 1e30f, b5 = 1e30f, b6 = 1e30f;
    int   n0 = 0, n1 = 0, n2 = 0, n3 = 0, n4 = 0, n5 = 0, n6 = 0;

    for (int j = 0; j < NPG; ++j) {
        if (j == t) continue;  // no self-loops (ref adds 1e10 on diagonal)
        const float dx = mx - px[j];
        const float dy = my - py[j];
        const float dz = mz - pz[j];
        const float d2 = dx * dx + dy * dy + dz * dz;
        if (d2 < b6) {
            b6 = d2; n6 = j;
#define CSWAP(da, ia, db, ib) \
            if (db < da) { float _t = da; da = db; db = _t; int _i = ia; ia = ib; ib = _i; }
            CSWAP(b5, n5, b6, n6)
            CSWAP(b4, n4, b5, n5)
            CSWAP(b3, n3, b4, n4)
            CSWAP(b2, n2, b3, n3)
            CSWAP(b1, n1, b2, n2)
            CSWAP(b0, n0, b1, n1)
#undef CSWAP
        }
    }
    const int base = (g * NPG + t) * KNN;
    const int off = g * NPG;
    knn[base + 0] = off + n0;
    knn[base + 1] = off + n1;
    knn[base + 2] = off + n2;
    knn[base + 3] = off + n3;
    knn[base + 4] = off + n4;
    knn[base + 5] = off + n5;
    knn[base + 6] = off + n6;
}

// ---------------------------------------------------------------------------
// Kernel 2: fused xl1 = x@Wl1+bl1, xr1 = x@Wr1+br1  ([N,10]@[10,64]).
// One thread per (node, ch4): float4 accumulators for both outputs.
// ---------------------------------------------------------------------------
__global__ __launch_bounds__(256) void lin1_kernel(const float* __restrict__ x,
                                                   const float* __restrict__ Wl,
                                                   const float* __restrict__ bl,
                                                   const float* __restrict__ Wr,
                                                   const float* __restrict__ br,
                                                   float* __restrict__ xl1,
                                                   float* __restrict__ xr1) {
    const int idx = blockIdx.x * 256 + threadIdx.x;   // N*16
    const int c4 = idx & 15;
    const size_t node = (size_t)(idx >> 4);
    const float* xrow = x + node * 10;
    f4 al = ((const f4*)bl)[c4];
    f4 ar = ((const f4*)br)[c4];
#pragma unroll
    for (int k = 0; k < 10; ++k) {
        const float xv = xrow[k];
        al += xv * ((const f4*)(Wl + k * 64))[c4];
        ar += xv * ((const f4*)(Wr + k * 64))[c4];
    }
    ((f4*)(xl1 + node * 64))[c4] = al;
    ((f4*)(xr1 + node * 64))[c4] = ar;
}

// ---------------------------------------------------------------------------
// Kernel 3: GATv2 layer-1 aggregation. One thread per (node, head), C=16.
// Two-pass over the 7 neighbors: pass1 alpha (in-thread dot, no shuffles),
// pass2 weighted sum (reloads hit L1/L2).
// ---------------------------------------------------------------------------
__global__ __launch_bounds__(256) void agg1_kernel(const float* __restrict__ xl,
                                                   const float* __restrict__ xr,
                                                   const int* __restrict__ knn,
                                                   const float* __restrict__ att,
                                                   const float* __restrict__ bias,
                                                   float* __restrict__ out) {
    const int idx = blockIdx.x * 256 + threadIdx.x;   // N*4
    const int h = idx & 3;
    const size_t node = (size_t)(idx >> 2);
    const int* nb = knn + node * KNN;
    int j[KNN];
#pragma unroll
    for (int k = 0; k < KNN; ++k) j[k] = nb[k];

    f4 xr4[4], at4[4];
    const f4* xrp = (const f4*)(xr + node * 64 + h * 16);
    const f4* atp = (const f4*)(att + h * 16);
#pragma unroll
    for (int i = 0; i < 4; ++i) { xr4[i] = xrp[i]; at4[i] = atp[i]; }

    float alpha[KNN];
#pragma unroll
    for (int k = 0; k < KNN; ++k) {
        const f4* xlp = (const f4*)(xl + (size_t)j[k] * 64 + h * 16);
        float s = 0.f;
#pragma unroll
        for (int i = 0; i < 4; ++i) {
            const f4 m = xlp[i] + xr4[i];
#pragma unroll
            for (int c = 0; c < 4; ++c) {
                float mm = m[c];
                mm = mm > 0.f ? mm : 0.2f * mm;   // leaky_relu(., 0.2)
                s += mm * at4[i][c];
            }
        }
        alpha[k] = s;
    }
    float amax = alpha[0];
#pragma unroll
    for (int k = 1; k < KNN; ++k) amax = fmaxf(amax, alpha[k]);
    float e[KNN];
    float denom = 0.f;
#pragma unroll
    for (int k = 0; k < KNN; ++k) { e[k] = expf(alpha[k] - amax); denom += e[k]; }
    const float rd = 1.f / denom;

    f4 o4[4];
#pragma unroll
    for (int i = 0; i < 4; ++i) o4[i] = 0.f;
#pragma unroll
    for (int k = 0; k < KNN; ++k) {
        const f4* xlp = (const f4*)(xl + (size_t)j[k] * 64 + h * 16);
#pragma unroll
        for (int i = 0; i < 4; ++i) o4[i] += e[k] * xlp[i];
    }
    const f4* bp = (const f4*)(bias + h * 16);
    f4* op = (f4*)(out + node * 64 + h * 16);
#pragma unroll
    for (int i = 0; i < 4; ++i) op[i] = o4[i] * rd + bp[i];
}

// ---------------------------------------------------------------------------
// Kernel 4: fused xl2 = h1@Wl2+bl2, xr2 = h1@Wr2+br2 as an LDS-tiled GEMM.
// Block = 64 nodes x 256 cols (Wl cols 0..127, Wr cols 128..255).
// Thread t: col-quad c = t&63 (4 consecutive cols), node-subtile s = t>>6
// (16 nodes). h tile [64][64] staged in LDS; inner loop = 4 W f4 loads
// (L1-hit) + 16 LDS broadcast f4 reads + 64 v_fmac. 16 f4 accumulators.
// ---------------------------------------------------------------------------
__global__ __launch_bounds__(256) void lin2_kernel(const float* __restrict__ h,
                                                   const float* __restrict__ Wl,
                                                   const float* __restrict__ bl,
                                                   const float* __restrict__ Wr,
                                                   const float* __restrict__ br,
                                                   float* __restrict__ xl2,
                                                   float* __restrict__ xr2) {
    __shared__ f4 hs[64 * 16];   // h tile [64 nodes][16 f4]
    const int tid = threadIdx.x;
    const size_t node0 = (size_t)blockIdx.x * 64;

    const f4* hg = (const f4*)(h + node0 * 64);
#pragma unroll
    for (int i = 0; i < 4; ++i) hs[tid + i * 256] = hg[tid + i * 256];
    __syncthreads();

    const int c = tid & 63;            // col-quad index (0..63)
    const int s = tid >> 6;            // node subtile (0..3), 16 nodes each
    const bool isR = c >= 32;
    const float* W = isR ? Wr : Wl;
    const float* bb = isR ? br : bl;
    float* dst = isR ? xr2 : xl2;
    const int cc = (c & 31) * 4;       // col offset within the 128-col matrix

    const f4 bias4 = *(const f4*)(bb + cc);
    f4 acc[16];
#pragma unroll
    for (int n = 0; n < 16; ++n) acc[n] = bias4;

    const f4* hrow = &hs[s * 16 * 16];  // this subtile's 16 node rows
#pragma unroll
    for (int k4 = 0; k4 < 16; ++k4) {
        const f4 w0 = *(const f4*)(W + (k4 * 4 + 0) * 128 + cc);
        const f4 w1 = *(const f4*)(W + (k4 * 4 + 1) * 128 + cc);
        const f4 w2 = *(const f4*)(W + (k4 * 4 + 2) * 128 + cc);
        const f4 w3 = *(const f4*)(W + (k4 * 4 + 3) * 128 + cc);
#pragma unroll
        for (int n = 0; n < 16; ++n) {
            const f4 hv = hrow[n * 16 + k4];   // wave-uniform -> LDS broadcast
            acc[n] += hv[0] * w0;
            acc[n] += hv[1] * w1;
            acc[n] += hv[2] * w2;
            acc[n] += hv[3] * w3;
        }
    }
#pragma unroll
    for (int n = 0; n < 16; ++n)
        *(f4*)(dst + (node0 + s * 16 + n) * 128 + cc) = acc[n];
}

// ---------------------------------------------------------------------------
// Kernel 5: GATv2 layer-2 aggregation fused with block-level mean pooling.
// One thread per (node, head), C=32. Block = 256 threads = 64 nodes (all in
// one graph: 8 blocks per graph). Per-node outputs go to LDS, reduced
// deterministically to per-block partial sums (bias added in stage 2).
// ---------------------------------------------------------------------------
__global__ __launch_bounds__(256) void agg2_pool_kernel(const float* __restrict__ xl,
                                                        const float* __restrict__ xr,
                                                        const int* __restrict__ knn,
                                                        const float* __restrict__ att,
                                                        float* __restrict__ partial) {
    __shared__ float sm[64 * 128];
    const int tid = threadIdx.x;
    const int h = tid & 3;
    const int n64 = tid >> 2;
    const size_t node = (size_t)blockIdx.x * 64 + n64;
    const int* nb = knn + node * KNN;
    int j[KNN];
#pragma unroll
    for (int k = 0; k < KNN; ++k) j[k] = nb[k];

    f4 xr4[8], at4[8];
    const f4* xrp = (const f4*)(xr + node * 128 + h * 32);
    const f4* atp = (const f4*)(att + h * 32);
#pragma unroll
    for (int i = 0; i < 8; ++i) { xr4[i] = xrp[i]; at4[i] = atp[i]; }

    float alpha[KNN];
#pragma unroll
    for (int k = 0; k < KNN; ++k) {
        const f4* xlp = (const f4*)(xl + (size_t)j[k] * 128 + h * 32);
        float s = 0.f;
#pragma unroll
        for (int i = 0; i < 8; ++i) {
            const f4 m = xlp[i] + xr4[i];
#pragma unroll
            for (int c = 0; c < 4; ++c) {
                float mm = m[c];
                mm = mm > 0.f ? mm : 0.2f * mm;
                s += mm * at4[i][c];
            }
        }
        alpha[k] = s;
    }
    float amax = alpha[0];
#pragma unroll
    for (int k = 1; k < KNN; ++k) amax = fmaxf(amax, alpha[k]);
    float e[KNN];
    float denom = 0.f;
#pragma unroll
    for (int k = 0; k < KNN; ++k) { e[k] = expf(alpha[k] - amax); denom += e[k]; }
    const float rd = 1.f / denom;

    f4 o4[8];
#pragma unroll
    for (int i = 0; i < 8; ++i) o4[i] = 0.f;
#pragma unroll
    for (int k = 0; k < KNN; ++k) {
        const f4* xlp = (const f4*)(xl + (size_t)j[k] * 128 + h * 32);
#pragma unroll
        for (int i = 0; i < 8; ++i) o4[i] += e[k] * xlp[i];
    }

    // stage per-node result (x 1/denom, no bias) into LDS: sm[n64][h*32 + i]
    f4* smp = (f4*)sm;
#pragma unroll
    for (int i = 0; i < 8; ++i) smp[n64 * 32 + h * 8 + i] = o4[i] * rd;
    __syncthreads();

    // deterministic block reduce over the 64 nodes -> per-block partial [128]
    if (tid < 128) {
        float s = 0.f;
#pragma unroll 8
        for (int n = 0; n < 64; ++n) s += sm[n * 128 + tid];
        partial[(size_t)blockIdx.x * 128 + tid] = s;
    }
}

// ---------------------------------------------------------------------------
// Kernel 6: stage-2 pool. One block per graph; combines the 8 block partials,
// divides by NPG, adds bias2.
// ---------------------------------------------------------------------------
__global__ __launch_bounds__(128) void pool2_kernel(const float* __restrict__ partial,
                                                    const float* __restrict__ bias,
                                                    float* __restrict__ out) {
    const int g = blockIdx.x;
    const int c = threadIdx.x;
    float s = 0.f;
#pragma unroll
    for (int b = 0; b < 8; ++b) s += partial[(size_t)(g * 8 + b) * 128 + c];
    out[g * 128 + c] = s * (1.f / 512.f) + bias[c];
}

extern "C" void kernel_launch(void* const* d_in, const int* in_sizes, int n_in,
                              void* d_out, int out_size, void* d_ws, size_t ws_size,
                              hipStream_t stream) {
    const float* pos   = (const float*)d_in[0];
    const float* x     = (const float*)d_in[1];
    // d_in[2] = batch (implicit: nodes ordered by graph, NPG each) -- unused
    const float* Wl1   = (const float*)d_in[3];
    const float* bl1   = (const float*)d_in[4];
    const float* Wr1   = (const float*)d_in[5];
    const float* br1   = (const float*)d_in[6];
    const float* att1  = (const float*)d_in[7];
    const float* bias1 = (const float*)d_in[8];
    const float* Wl2   = (const float*)d_in[9];
    const float* bl2   = (const float*)d_in[10];
    const float* Wr2   = (const float*)d_in[11];
    const float* br2   = (const float*)d_in[12];
    const float* att2  = (const float*)d_in[13];
    const float* bias2 = (const float*)d_in[14];
    float* out = (float*)d_out;

    // Workspace layout (liveness-overlapped, total 171,442,176 B):
    //   [0,        3.67MB)  knn [N][7] int32                     (live: all)
    //   [3.67MB,  70.78MB)  slotA: xl1|xr1 [N][64]x2  -> xl2 [N][128]
    //   [70.78MB,104.33MB)  h1 [N][64]                -> partial [2048][128]
    //   [104.33, 171.44MB)  xr2 [N][128]
    char* ws = (char*)d_ws;
    int*   knn  = (int*)(ws + 0);
    float* xl1  = (float*)(ws + 3670016);
    float* xr1  = (float*)(ws + 37224448);
    float* h1   = (float*)(ws + 70778880);
    float* xl2  = (float*)(ws + 3670016);     // over dead xl1|xr1
    float* xr2  = (float*)(ws + 104333312);
    float* partial = (float*)(ws + 70778880); // over dead h1

    knn_kernel<<<B_GRAPHS, NPG, 0, stream>>>(pos, knn);
    lin1_kernel<<<(N_NODES * 16) / 256, 256, 0, stream>>>(x, Wl1, bl1, Wr1, br1, xl1, xr1);
    agg1_kernel<<<(N_NODES * 4) / 256, 256, 0, stream>>>(xl1, xr1, knn, att1, bias1, h1);
    lin2_kernel<<<N_NODES / 64, 256, 0, stream>>>(h1, Wl2, bl2, Wr2, br2, xl2, xr2);
    agg2_pool_kernel<<<N_NODES / 64, 256, 0, stream>>>(xl2, xr2, knn, att2, partial);
    pool2_kernel<<<B_GRAPHS, 128, 0, stream>>>(partial, bias2, out);
}

// Round 7
// 331.543 us; speedup vs baseline: 2.1412x; 1.0921x over previous
//
#include <hip/hip_runtime.h>
#include <hip/hip_bf16.h>

#define N_NODES 131072
#define B_GRAPHS 256
#define NPG 512
#define KNN 7
#define HEADS 4

using f4 = __attribute__((ext_vector_type(4))) float;

// ---------------------------------------------------------------------------
// Kernel 1: cooperative wave-per-query kNN (K=7).
// Block = 256 threads = 4 waves = 4 queries (all in one graph; 128 blocks per
// graph). Graph positions staged in LDS. Each lane computes 8 candidate
// distances (no divergence), sorts its 8 (d2, it) pairs with a 19-CE Batcher
// network in named registers, then 7 rounds of wave-min extraction.
// ---------------------------------------------------------------------------
__global__ __launch_bounds__(256) void knn_kernel(const float* __restrict__ pos,
                                                  int* __restrict__ knn) {
    __shared__ float sp[NPG * 3];
    const int tid = threadIdx.x;
    const int lane = tid & 63;
    const size_t node = (size_t)blockIdx.x * 4 + (tid >> 6);
    const int g = (int)(node >> 9);          // node / 512
    const int q = (int)(node & 511);         // local query index

    const float* p = pos + (size_t)g * NPG * 3;
    for (int i = tid; i < NPG * 3; i += 256) sp[i] = p[i];
    __syncthreads();

    const float qx = sp[q * 3 + 0];
    const float qy = sp[q * 3 + 1];
    const float qz = sp[q * 3 + 2];

    // 8 candidates per lane: c = (it<<6) | lane
    float d0, d1, d2_, d3, d4, d5, d6, d7;
    {
        float dd[8];
#pragma unroll
        for (int it = 0; it < 8; ++it) {
            const int c = (it << 6) | lane;
            const float dx = qx - sp[c * 3 + 0];
            const float dy = qy - sp[c * 3 + 1];
            const float dz = qz - sp[c * 3 + 2];
            float d = dx * dx + dy * dy + dz * dz;
            dd[it] = (c == q) ? 1e30f : d;   // no self-loop
        }
        d0 = dd[0]; d1 = dd[1]; d2_ = dd[2]; d3 = dd[3];
        d4 = dd[4]; d5 = dd[5]; d6 = dd[6]; d7 = dd[7];
    }
    int t0 = 0, t1 = 1, t2 = 2, t3 = 3, t4 = 4, t5 = 5, t6 = 6, t7 = 7;

    // Batcher odd-even mergesort, 19 compare-exchanges (ascending by d)
#define CE(da, ta, db, tb) { \
        const bool sw = db < da; \
        const float dmin = sw ? db : da; const float dmax = sw ? da : db; \
        const int   tmin = sw ? tb : ta; const int   tmax = sw ? ta : tb; \
        da = dmin; db = dmax; ta = tmin; tb = tmax; }
    CE(d0,t0,d1,t1) CE(d2_,t2,d3,t3) CE(d4,t4,d5,t5) CE(d6,t6,d7,t7)
    CE(d0,t0,d2_,t2) CE(d1,t1,d3,t3) CE(d4,t4,d6,t6) CE(d5,t5,d7,t7)
    CE(d1,t1,d2_,t2) CE(d5,t5,d6,t6)
    CE(d0,t0,d4,t4) CE(d1,t1,d5,t5) CE(d2_,t2,d6,t6) CE(d3,t3,d7,t7)
    CE(d2_,t2,d4,t4) CE(d3,t3,d5,t5)
    CE(d1,t1,d2_,t2) CE(d3,t3,d4,t4) CE(d5,t5,d6,t6)
#undef CE

    int myneigh = 0;
#pragma unroll
    for (int r = 0; r < KNN; ++r) {
        // wave-min over heads
        float m = d0;
        m = fminf(m, __shfl_xor(m, 1));
        m = fminf(m, __shfl_xor(m, 2));
        m = fminf(m, __shfl_xor(m, 4));
        m = fminf(m, __shfl_xor(m, 8));
        m = fminf(m, __shfl_xor(m, 16));
        m = fminf(m, __shfl_xor(m, 32));
        const unsigned long long b = __ballot(d0 == m);
        const int winlane = __ffsll((long long)b) - 1;
        const int cand = (t0 << 6) | lane;
        const int widx = __shfl(cand, winlane);
        if (lane == r) myneigh = widx;
        if (lane == winlane) {   // pop head
            d0 = d1; d1 = d2_; d2_ = d3; d3 = d4; d4 = d5; d5 = d6; d6 = d7; d7 = 1e30f;
            t0 = t1; t1 = t2; t2 = t3; t3 = t4; t4 = t5; t5 = t6; t6 = t7;
        }
    }
    if (lane < KNN) knn[node * KNN + lane] = g * NPG + myneigh;
}

// ---------------------------------------------------------------------------
// Kernel 2: fused xl1 = x@Wl1+bl1, xr1 = x@Wr1+br1  ([N,10]@[10,64]).
// One thread per (node, ch4): float4 accumulators for both outputs.
// ---------------------------------------------------------------------------
__global__ __launch_bounds__(256) void lin1_kernel(const float* __restrict__ x,
                                                   const float* __restrict__ Wl,
                                                   const float* __restrict__ bl,
                                                   const float* __restrict__ Wr,
                                                   const float* __restrict__ br,
                                                   float* __restrict__ xl1,
                                                   float* __restrict__ xr1) {
    const int idx = blockIdx.x * 256 + threadIdx.x;   // N*16
    const int c4 = idx & 15;
    const size_t node = (size_t)(idx >> 4);
    const float* xrow = x + node * 10;
    f4 al = ((const f4*)bl)[c4];
    f4 ar = ((const f4*)br)[c4];
#pragma unroll
    for (int k = 0; k < 10; ++k) {
        const float xv = xrow[k];
        al += xv * ((const f4*)(Wl + k * 64))[c4];
        ar += xv * ((const f4*)(Wr + k * 64))[c4];
    }
    ((f4*)(xl1 + node * 64))[c4] = al;
    ((f4*)(xr1 + node * 64))[c4] = ar;
}

// ---------------------------------------------------------------------------
// Kernel 3: GATv2 layer-1 aggregation. One thread per (node, head), C=16.
// Two-pass over the 7 neighbors: pass1 alpha (in-thread dot, no shuffles),
// pass2 weighted sum (reloads hit L1/L2).
// ---------------------------------------------------------------------------
__global__ __launch_bounds__(256) void agg1_kernel(const float* __restrict__ xl,
                                                   const float* __restrict__ xr,
                                                   const int* __restrict__ knn,
                                                   const float* __restrict__ att,
                                                   const float* __restrict__ bias,
                                                   float* __restrict__ out) {
    const int idx = blockIdx.x * 256 + threadIdx.x;   // N*4
    const int h = idx & 3;
    const size_t node = (size_t)(idx >> 2);
    const int* nb = knn + node * KNN;
    int j[KNN];
#pragma unroll
    for (int k = 0; k < KNN; ++k) j[k] = nb[k];

    f4 xr4[4], at4[4];
    const f4* xrp = (const f4*)(xr + node * 64 + h * 16);
    const f4* atp = (const f4*)(att + h * 16);
#pragma unroll
    for (int i = 0; i < 4; ++i) { xr4[i] = xrp[i]; at4[i] = atp[i]; }

    float alpha[KNN];
#pragma unroll
    for (int k = 0; k < KNN; ++k) {
        const f4* xlp = (const f4*)(xl + (size_t)j[k] * 64 + h * 16);
        float s = 0.f;
#pragma unroll
        for (int i = 0; i < 4; ++i) {
            const f4 m = xlp[i] + xr4[i];
#pragma unroll
            for (int c = 0; c < 4; ++c) {
                float mm = m[c];
                mm = mm > 0.f ? mm : 0.2f * mm;   // leaky_relu(., 0.2)
                s += mm * at4[i][c];
            }
        }
        alpha[k] = s;
    }
    float amax = alpha[0];
#pragma unroll
    for (int k = 1; k < KNN; ++k) amax = fmaxf(amax, alpha[k]);
    float e[KNN];
    float denom = 0.f;
#pragma unroll
    for (int k = 0; k < KNN; ++k) { e[k] = expf(alpha[k] - amax); denom += e[k]; }
    const float rd = 1.f / denom;

    f4 o4[4];
#pragma unroll
    for (int i = 0; i < 4; ++i) o4[i] = 0.f;
#pragma unroll
    for (int k = 0; k < KNN; ++k) {
        const f4* xlp = (const f4*)(xl + (size_t)j[k] * 64 + h * 16);
#pragma unroll
        for (int i = 0; i < 4; ++i) o4[i] += e[k] * xlp[i];
    }
    const f4* bp = (const f4*)(bias + h * 16);
    f4* op = (f4*)(out + node * 64 + h * 16);
#pragma unroll
    for (int i = 0; i < 4; ++i) op[i] = o4[i] * rd + bp[i];
}

// ---------------------------------------------------------------------------
// Kernel 4: fused xl2 = h1@Wl2+bl2, xr2 = h1@Wr2+br2 as an LDS-tiled GEMM.
// Block = 64 nodes x 256 cols (Wl cols 0..127, Wr cols 128..255).
// ---------------------------------------------------------------------------
__global__ __launch_bounds__(256) void lin2_kernel(const float* __restrict__ h,
                                                   const float* __restrict__ Wl,
                                                   const float* __restrict__ bl,
                                                   const float* __restrict__ Wr,
                                                   const float* __restrict__ br,
                                                   float* __restrict__ xl2,
                                                   float* __restrict__ xr2) {
    __shared__ f4 hs[64 * 16];   // h tile [64 nodes][16 f4]
    const int tid = threadIdx.x;
    const size_t node0 = (size_t)blockIdx.x * 64;

    const f4* hg = (const f4*)(h + node0 * 64);
#pragma unroll
    for (int i = 0; i < 4; ++i) hs[tid + i * 256] = hg[tid + i * 256];
    __syncthreads();

    const int c = tid & 63;            // col-quad index (0..63)
    const int s = tid >> 6;            // node subtile (0..3), 16 nodes each
    const bool isR = c >= 32;
    const float* W = isR ? Wr : Wl;
    const float* bb = isR ? br : bl;
    float* dst = isR ? xr2 : xl2;
    const int cc = (c & 31) * 4;       // col offset within the 128-col matrix

    const f4 bias4 = *(const f4*)(bb + cc);
    f4 acc[16];
#pragma unroll
    for (int n = 0; n < 16; ++n) acc[n] = bias4;

    const f4* hrow = &hs[s * 16 * 16];  // this subtile's 16 node rows
#pragma unroll
    for (int k4 = 0; k4 < 16; ++k4) {
        const f4 w0 = *(const f4*)(W + (k4 * 4 + 0) * 128 + cc);
        const f4 w1 = *(const f4*)(W + (k4 * 4 + 1) * 128 + cc);
        const f4 w2 = *(const f4*)(W + (k4 * 4 + 2) * 128 + cc);
        const f4 w3 = *(const f4*)(W + (k4 * 4 + 3) * 128 + cc);
#pragma unroll
        for (int n = 0; n < 16; ++n) {
            const f4 hv = hrow[n * 16 + k4];   // wave-uniform -> LDS broadcast
            acc[n] += hv[0] * w0;
            acc[n] += hv[1] * w1;
            acc[n] += hv[2] * w2;
            acc[n] += hv[3] * w3;
        }
    }
#pragma unroll
    for (int n = 0; n < 16; ++n)
        *(f4*)(dst + (node0 + s * 16 + n) * 128 + cc) = acc[n];
}

// ---------------------------------------------------------------------------
// Kernel 5: GATv2 layer-2 aggregation fused with block-level mean pooling.
// One thread per (node, head), C=32. Block = 256 threads = 64 nodes (all in
// one graph: 8 blocks per graph). Per-node outputs go to LDS, reduced
// deterministically to per-block partial sums (bias added in stage 2).
// ---------------------------------------------------------------------------
__global__ __launch_bounds__(256) void agg2_pool_kernel(const float* __restrict__ xl,
                                                        const float* __restrict__ xr,
                                                        const int* __restrict__ knn,
                                                        const float* __restrict__ att,
                                                        float* __restrict__ partial) {
    __shared__ float sm[64 * 128];
    const int tid = threadIdx.x;
    const int h = tid & 3;
    const int n64 = tid >> 2;
    const size_t node = (size_t)blockIdx.x * 64 + n64;
    const int* nb = knn + node * KNN;
    int j[KNN];
#pragma unroll
    for (int k = 0; k < KNN; ++k) j[k] = nb[k];

    f4 xr4[8], at4[8];
    const f4* xrp = (const f4*)(xr + node * 128 + h * 32);
    const f4* atp = (const f4*)(att + h * 32);
#pragma unroll
    for (int i = 0; i < 8; ++i) { xr4[i] = xrp[i]; at4[i] = atp[i]; }

    float alpha[KNN];
#pragma unroll
    for (int k = 0; k < KNN; ++k) {
        const f4* xlp = (const f4*)(xl + (size_t)j[k] * 128 + h * 32);
        float s = 0.f;
#pragma unroll
        for (int i = 0; i < 8; ++i) {
            const f4 m = xlp[i] + xr4[i];
#pragma unroll
            for (int c = 0; c < 4; ++c) {
                float mm = m[c];
                mm = mm > 0.f ? mm : 0.2f * mm;
                s += mm * at4[i][c];
            }
        }
        alpha[k] = s;
    }
    float amax = alpha[0];
#pragma unroll
    for (int k = 1; k < KNN; ++k) amax = fmaxf(amax, alpha[k]);
    float e[KNN];
    float denom = 0.f;
#pragma unroll
    for (int k = 0; k < KNN; ++k) { e[k] = expf(alpha[k] - amax); denom += e[k]; }
    const float rd = 1.f / denom;

    f4 o4[8];
#pragma unroll
    for (int i = 0; i < 8; ++i) o4[i] = 0.f;
#pragma unroll
    for (int k = 0; k < KNN; ++k) {
        const f4* xlp = (const f4*)(xl + (size_t)j[k] * 128 + h * 32);
#pragma unroll
        for (int i = 0; i < 8; ++i) o4[i] += e[k] * xlp[i];
    }

    // stage per-node result (x 1/denom, no bias) into LDS: sm[n64][h*32 + i]
    f4* smp = (f4*)sm;
#pragma unroll
    for (int i = 0; i < 8; ++i) smp[n64 * 32 + h * 8 + i] = o4[i] * rd;
    __syncthreads();

    // deterministic block reduce over the 64 nodes -> per-block partial [128]
    if (tid < 128) {
        float s = 0.f;
#pragma unroll 8
        for (int n = 0; n < 64; ++n) s += sm[n * 128 + tid];
        partial[(size_t)blockIdx.x * 128 + tid] = s;
    }
}

// ---------------------------------------------------------------------------
// Kernel 6: stage-2 pool. One block per graph; combines the 8 block partials,
// divides by NPG, adds bias2.
// ---------------------------------------------------------------------------
__global__ __launch_bounds__(128) void pool2_kernel(const float* __restrict__ partial,
                                                    const float* __restrict__ bias,
                                                    float* __restrict__ out) {
    const int g = blockIdx.x;
    const int c = threadIdx.x;
    float s = 0.f;
#pragma unroll
    for (int b = 0; b < 8; ++b) s += partial[(size_t)(g * 8 + b) * 128 + c];
    out[g * 128 + c] = s * (1.f / 512.f) + bias[c];
}

extern "C" void kernel_launch(void* const* d_in, const int* in_sizes, int n_in,
                              void* d_out, int out_size, void* d_ws, size_t ws_size,
                              hipStream_t stream) {
    const float* pos   = (const float*)d_in[0];
    const float* x     = (const float*)d_in[1];
    // d_in[2] = batch (implicit: nodes ordered by graph, NPG each) -- unused
    const float* Wl1   = (const float*)d_in[3];
    const float* bl1   = (const float*)d_in[4];
    const float* Wr1   = (const float*)d_in[5];
    const float* br1   = (const float*)d_in[6];
    const float* att1  = (const float*)d_in[7];
    const float* bias1 = (const float*)d_in[8];
    const float* Wl2   = (const float*)d_in[9];
    const float* bl2   = (const float*)d_in[10];
    const float* Wr2   = (const float*)d_in[11];
    const float* br2   = (const float*)d_in[12];
    const float* att2  = (const float*)d_in[13];
    const float* bias2 = (const float*)d_in[14];
    float* out = (float*)d_out;

    // Workspace layout (liveness-overlapped, total 171,442,176 B):
    //   [0,        3.67MB)  knn [N][7] int32                     (live: all)
    //   [3.67MB,  70.78MB)  slotA: xl1|xr1 [N][64]x2  -> xl2 [N][128]
    //   [70.78MB,104.33MB)  h1 [N][64]                -> partial [2048][128]
    //   [104.33, 171.44MB)  xr2 [N][128]
    char* ws = (char*)d_ws;
    int*   knn  = (int*)(ws + 0);
    float* xl1  = (float*)(ws + 3670016);
    float* xr1  = (float*)(ws + 37224448);
    float* h1   = (float*)(ws + 70778880);
    float* xl2  = (float*)(ws + 3670016);     // over dead xl1|xr1
    float* xr2  = (float*)(ws + 104333312);
    float* partial = (float*)(ws + 70778880); // over dead h1

    knn_kernel<<<N_NODES / 4, 256, 0, stream>>>(pos, knn);
    lin1_kernel<<<(N_NODES * 16) / 256, 256, 0, stream>>>(x, Wl1, bl1, Wr1, br1, xl1, xr1);
    agg1_kernel<<<(N_NODES * 4) / 256, 256, 0, stream>>>(xl1, xr1, knn, att1, bias1, h1);
    lin2_kernel<<<N_NODES / 64, 256, 0, stream>>>(h1, Wl2, bl2, Wr2, br2, xl2, xr2);
    agg2_pool_kernel<<<N_NODES / 64, 256, 0, stream>>>(xl2, xr2, knn, att2, partial);
    pool2_kernel<<<B_GRAPHS, 128, 0, stream>>>(partial, bias2, out);
}

// Round 8
// 276.779 us; speedup vs baseline: 2.5648x; 1.1979x over previous
//
#include <hip/hip_runtime.h>
#include <hip/hip_bf16.h>

#define N_NODES 131072
#define B_GRAPHS 256
#define NPG 512
#define KNN 7
#define HEADS 4

using f4 = __attribute__((ext_vector_type(4))) float;
using short8 = __attribute__((ext_vector_type(8))) short;  // 8 bf16 (4 VGPRs)

__device__ __forceinline__ unsigned short f2bf(float f) {   // RNE f32->bf16
    unsigned u = __builtin_bit_cast(unsigned, f);
    u += 0x7FFFu + ((u >> 16) & 1u);
    return (unsigned short)(u >> 16);
}

// ---------------------------------------------------------------------------
// Kernel 1: cooperative wave-per-query kNN (K=7). (unchanged from round 7:
// VALUBusy 95%, occupancy 84% -- at its algorithmic issue roofline)
// ---------------------------------------------------------------------------
__global__ __launch_bounds__(256) void knn_kernel(const float* __restrict__ pos,
                                                  int* __restrict__ knn) {
    __shared__ float sp[NPG * 3];
    const int tid = threadIdx.x;
    const int lane = tid & 63;
    const size_t node = (size_t)blockIdx.x * 4 + (tid >> 6);
    const int g = (int)(node >> 9);
    const int q = (int)(node & 511);

    const float* p = pos + (size_t)g * NPG * 3;
    for (int i = tid; i < NPG * 3; i += 256) sp[i] = p[i];
    __syncthreads();

    const float qx = sp[q * 3 + 0];
    const float qy = sp[q * 3 + 1];
    const float qz = sp[q * 3 + 2];

    float d0, d1, d2_, d3, d4, d5, d6, d7;
    {
        float dd[8];
#pragma unroll
        for (int it = 0; it < 8; ++it) {
            const int c = (it << 6) | lane;
            const float dx = qx - sp[c * 3 + 0];
            const float dy = qy - sp[c * 3 + 1];
            const float dz = qz - sp[c * 3 + 2];
            float d = dx * dx + dy * dy + dz * dz;
            dd[it] = (c == q) ? 1e30f : d;
        }
        d0 = dd[0]; d1 = dd[1]; d2_ = dd[2]; d3 = dd[3];
        d4 = dd[4]; d5 = dd[5]; d6 = dd[6]; d7 = dd[7];
    }
    int t0 = 0, t1 = 1, t2 = 2, t3 = 3, t4 = 4, t5 = 5, t6 = 6, t7 = 7;

#define CE(da, ta, db, tb) { \
        const bool sw = db < da; \
        const float dmin = sw ? db : da; const float dmax = sw ? da : db; \
        const int   tmin = sw ? tb : ta; const int   tmax = sw ? ta : tb; \
        da = dmin; db = dmax; ta = tmin; tb = tmax; }
    CE(d0,t0,d1,t1) CE(d2_,t2,d3,t3) CE(d4,t4,d5,t5) CE(d6,t6,d7,t7)
    CE(d0,t0,d2_,t2) CE(d1,t1,d3,t3) CE(d4,t4,d6,t6) CE(d5,t5,d7,t7)
    CE(d1,t1,d2_,t2) CE(d5,t5,d6,t6)
    CE(d0,t0,d4,t4) CE(d1,t1,d5,t5) CE(d2_,t2,d6,t6) CE(d3,t3,d7,t7)
    CE(d2_,t2,d4,t4) CE(d3,t3,d5,t5)
    CE(d1,t1,d2_,t2) CE(d3,t3,d4,t4) CE(d5,t5,d6,t6)
#undef CE

    int myneigh = 0;
#pragma unroll
    for (int r = 0; r < KNN; ++r) {
        float m = d0;
        m = fminf(m, __shfl_xor(m, 1));
        m = fminf(m, __shfl_xor(m, 2));
        m = fminf(m, __shfl_xor(m, 4));
        m = fminf(m, __shfl_xor(m, 8));
        m = fminf(m, __shfl_xor(m, 16));
        m = fminf(m, __shfl_xor(m, 32));
        const unsigned long long b = __ballot(d0 == m);
        const int winlane = __ffsll((long long)b) - 1;
        const int cand = (t0 << 6) | lane;
        const int widx = __shfl(cand, winlane);
        if (lane == r) myneigh = widx;
        if (lane == winlane) {
            d0 = d1; d1 = d2_; d2_ = d3; d3 = d4; d4 = d5; d5 = d6; d6 = d7; d7 = 1e30f;
            t0 = t1; t1 = t2; t2 = t3; t3 = t4; t4 = t5; t5 = t6; t6 = t7;
        }
    }
    if (lane < KNN) knn[node * KNN + lane] = g * NPG + myneigh;
}

// ---------------------------------------------------------------------------
// Kernel 2: fused xl1 = x@Wl1+bl1, xr1 = x@Wr1+br1  ([N,10]@[10,64]).
// ---------------------------------------------------------------------------
__global__ __launch_bounds__(256) void lin1_kernel(const float* __restrict__ x,
                                                   const float* __restrict__ Wl,
                                                   const float* __restrict__ bl,
                                                   const float* __restrict__ Wr,
                                                   const float* __restrict__ br,
                                                   float* __restrict__ xl1,
                                                   float* __restrict__ xr1) {
    const int idx = blockIdx.x * 256 + threadIdx.x;   // N*16
    const int c4 = idx & 15;
    const size_t node = (size_t)(idx >> 4);
    const float* xrow = x + node * 10;
    f4 al = ((const f4*)bl)[c4];
    f4 ar = ((const f4*)br)[c4];
#pragma unroll
    for (int k = 0; k < 10; ++k) {
        const float xv = xrow[k];
        al += xv * ((const f4*)(Wl + k * 64))[c4];
        ar += xv * ((const f4*)(Wr + k * 64))[c4];
    }
    ((f4*)(xl1 + node * 64))[c4] = al;
    ((f4*)(xr1 + node * 64))[c4] = ar;
}

// ---------------------------------------------------------------------------
// Kernel 3: GATv2 layer-1 aggregation. One thread per (node, head), C=16.
// Writes h1 as bf16 (its only consumer is the MFMA lin2).
// ---------------------------------------------------------------------------
__global__ __launch_bounds__(256) void agg1_kernel(const float* __restrict__ xl,
                                                   const float* __restrict__ xr,
                                                   const int* __restrict__ knn,
                                                   const float* __restrict__ att,
                                                   const float* __restrict__ bias,
                                                   unsigned short* __restrict__ h1b) {
    const int idx = blockIdx.x * 256 + threadIdx.x;   // N*4
    const int h = idx & 3;
    const size_t node = (size_t)(idx >> 2);
    const int* nb = knn + node * KNN;
    int j[KNN];
#pragma unroll
    for (int k = 0; k < KNN; ++k) j[k] = nb[k];

    f4 xr4[4], at4[4];
    const f4* xrp = (const f4*)(xr + node * 64 + h * 16);
    const f4* atp = (const f4*)(att + h * 16);
#pragma unroll
    for (int i = 0; i < 4; ++i) { xr4[i] = xrp[i]; at4[i] = atp[i]; }

    float alpha[KNN];
#pragma unroll
    for (int k = 0; k < KNN; ++k) {
        const f4* xlp = (const f4*)(xl + (size_t)j[k] * 64 + h * 16);
        float s = 0.f;
#pragma unroll
        for (int i = 0; i < 4; ++i) {
            const f4 m = xlp[i] + xr4[i];
#pragma unroll
            for (int c = 0; c < 4; ++c) {
                float mm = m[c];
                mm = mm > 0.f ? mm : 0.2f * mm;   // leaky_relu(., 0.2)
                s += mm * at4[i][c];
            }
        }
        alpha[k] = s;
    }
    float amax = alpha[0];
#pragma unroll
    for (int k = 1; k < KNN; ++k) amax = fmaxf(amax, alpha[k]);
    float e[KNN];
    float denom = 0.f;
#pragma unroll
    for (int k = 0; k < KNN; ++k) { e[k] = expf(alpha[k] - amax); denom += e[k]; }
    const float rd = 1.f / denom;

    f4 o4[4];
#pragma unroll
    for (int i = 0; i < 4; ++i) o4[i] = 0.f;
#pragma unroll
    for (int k = 0; k < KNN; ++k) {
        const f4* xlp = (const f4*)(xl + (size_t)j[k] * 64 + h * 16);
#pragma unroll
        for (int i = 0; i < 4; ++i) o4[i] += e[k] * xlp[i];
    }
    const f4* bp = (const f4*)(bias + h * 16);
    short8 r0, r1;
#pragma unroll
    for (int i = 0; i < 4; ++i) {
        const f4 v = o4[i] * rd + bp[i];
#pragma unroll
        for (int c = 0; c < 4; ++c) {
            const unsigned short bv = f2bf(v[c]);
            const int e4 = i * 4 + c;
            if (e4 < 8) r0[e4] = (short)bv; else r1[e4 - 8] = (short)bv;
        }
    }
    short8* hp = (short8*)(h1b + node * 64 + h * 16);
    hp[0] = r0;
    hp[1] = r1;
}

// ---------------------------------------------------------------------------
// Kernel 4a: pack Wl2||Wr2 (f32 [64][128] each) into bf16 MFMA B-fragment
// layout: wbf[(kb*256 + n)*8 + i] = W[kb*8+i][n], kb=k>>3. Lane's 8 k-values
// become one contiguous 16B load.
// ---------------------------------------------------------------------------
__global__ __launch_bounds__(256) void wprep_kernel(const float* __restrict__ Wl,
                                                    const float* __restrict__ Wr,
                                                    unsigned short* __restrict__ wbf) {
    const int t = blockIdx.x * 256 + threadIdx.x;   // 64*256 = 16384
    const int k = t >> 8;       // 0..63
    const int n = t & 255;      // 0..255
    const float v = (n < 128) ? Wl[k * 128 + n] : Wr[k * 128 + (n - 128)];
    wbf[((k >> 3) * 256 + n) * 8 + (k & 7)] = f2bf(v);
}

// ---------------------------------------------------------------------------
// Kernel 4b: lin2 via MFMA. Block = 256 thr = 4 waves = 16 nodes x 256 cols.
// Wave w owns cols [w*64, w*64+64) (4 16x16 tiles, K=64 -> 2 MFMA each).
// A-frag: lane holds h1b[node0+(l&15)][(l>>4)*8 .. +8]. B-frag from wbf.
// C/D: col=lane&15, row=(lane>>4)*4+reg  [m89/m91-verified mapping].
// Bias preloaded into accumulator. No LDS.
// ---------------------------------------------------------------------------
__global__ __launch_bounds__(256) void lin2_kernel(const unsigned short* __restrict__ h1b,
                                                   const unsigned short* __restrict__ wbf,
                                                   const float* __restrict__ bl,
                                                   const float* __restrict__ br,
                                                   float* __restrict__ xl2,
                                                   float* __restrict__ xr2) {
    const int tid = threadIdx.x;
    const int lane = tid & 63;
    const int w = tid >> 6;
    const size_t node0 = (size_t)blockIdx.x * 16;
    const int lm = lane & 15, lk = lane >> 4;

    const short8* hp = (const short8*)h1b;
    const short8 a0 = hp[(node0 + lm) * 8 + lk];       // k = lk*8 .. +8
    const short8 a1 = hp[(node0 + lm) * 8 + lk + 4];   // k = 32 + lk*8 .. +8

    const short8* wp = (const short8*)wbf;
#pragma unroll
    for (int t = 0; t < 4; ++t) {
        const int col = w * 64 + t * 16 + lm;          // 0..255 (uniform half per wave)
        const float bias = (col < 128) ? bl[col] : br[col - 128];
        f4 acc = {bias, bias, bias, bias};
        const short8 b0 = wp[lk * 256 + col];
        const short8 b1 = wp[(lk + 4) * 256 + col];
        acc = __builtin_amdgcn_mfma_f32_16x16x32_bf16(a0, b0, acc, 0, 0, 0);
        acc = __builtin_amdgcn_mfma_f32_16x16x32_bf16(a1, b1, acc, 0, 0, 0);
        float* dst = (col < 128) ? (xl2 + col) : (xr2 + (col - 128));
#pragma unroll
        for (int r = 0; r < 4; ++r)
            dst[(node0 + lk * 4 + r) * 128] = acc[r];
    }
}

// ---------------------------------------------------------------------------
// Kernel 5: GATv2 layer-2 aggregation fused with block-level mean pooling.
// ---------------------------------------------------------------------------
__global__ __launch_bounds__(256) void agg2_pool_kernel(const float* __restrict__ xl,
                                                        const float* __restrict__ xr,
                                                        const int* __restrict__ knn,
                                                        const float* __restrict__ att,
                                                        float* __restrict__ partial) {
    __shared__ float sm[64 * 128];
    const int tid = threadIdx.x;
    const int h = tid & 3;
    const int n64 = tid >> 2;
    const size_t node = (size_t)blockIdx.x * 64 + n64;
    const int* nb = knn + node * KNN;
    int j[KNN];
#pragma unroll
    for (int k = 0; k < KNN; ++k) j[k] = nb[k];

    f4 xr4[8], at4[8];
    const f4* xrp = (const f4*)(xr + node * 128 + h * 32);
    const f4* atp = (const f4*)(att + h * 32);
#pragma unroll
    for (int i = 0; i < 8; ++i) { xr4[i] = xrp[i]; at4[i] = atp[i]; }

    float alpha[KNN];
#pragma unroll
    for (int k = 0; k < KNN; ++k) {
        const f4* xlp = (const f4*)(xl + (size_t)j[k] * 128 + h * 32);
        float s = 0.f;
#pragma unroll
        for (int i = 0; i < 8; ++i) {
            const f4 m = xlp[i] + xr4[i];
#pragma unroll
            for (int c = 0; c < 4; ++c) {
                float mm = m[c];
                mm = mm > 0.f ? mm : 0.2f * mm;
                s += mm * at4[i][c];
            }
        }
        alpha[k] = s;
    }
    float amax = alpha[0];
#pragma unroll
    for (int k = 1; k < KNN; ++k) amax = fmaxf(amax, alpha[k]);
    float e[KNN];
    float denom = 0.f;
#pragma unroll
    for (int k = 0; k < KNN; ++k) { e[k] = expf(alpha[k] - amax); denom += e[k]; }
    const float rd = 1.f / denom;

    f4 o4[8];
#pragma unroll
    for (int i = 0; i < 8; ++i) o4[i] = 0.f;
#pragma unroll
    for (int k = 0; k < KNN; ++k) {
        const f4* xlp = (const f4*)(xl + (size_t)j[k] * 128 + h * 32);
#pragma unroll
        for (int i = 0; i < 8; ++i) o4[i] += e[k] * xlp[i];
    }

    f4* smp = (f4*)sm;
#pragma unroll
    for (int i = 0; i < 8; ++i) smp[n64 * 32 + h * 8 + i] = o4[i] * rd;
    __syncthreads();

    if (tid < 128) {
        float s = 0.f;
#pragma unroll 8
        for (int n = 0; n < 64; ++n) s += sm[n * 128 + tid];
        partial[(size_t)blockIdx.x * 128 + tid] = s;
    }
}

// ---------------------------------------------------------------------------
// Kernel 6: stage-2 pool.
// ---------------------------------------------------------------------------
__global__ __launch_bounds__(128) void pool2_kernel(const float* __restrict__ partial,
                                                    const float* __restrict__ bias,
                                                    float* __restrict__ out) {
    const int g = blockIdx.x;
    const int c = threadIdx.x;
    float s = 0.f;
#pragma unroll
    for (int b = 0; b < 8; ++b) s += partial[(size_t)(g * 8 + b) * 128 + c];
    out[g * 128 + c] = s * (1.f / 512.f) + bias[c];
}

extern "C" void kernel_launch(void* const* d_in, const int* in_sizes, int n_in,
                              void* d_out, int out_size, void* d_ws, size_t ws_size,
                              hipStream_t stream) {
    const float* pos   = (const float*)d_in[0];
    const float* x     = (const float*)d_in[1];
    const float* Wl1   = (const float*)d_in[3];
    const float* bl1   = (const float*)d_in[4];
    const float* Wr1   = (const float*)d_in[5];
    const float* br1   = (const float*)d_in[6];
    const float* att1  = (const float*)d_in[7];
    const float* bias1 = (const float*)d_in[8];
    const float* Wl2   = (const float*)d_in[9];
    const float* bl2   = (const float*)d_in[10];
    const float* Wr2   = (const float*)d_in[11];
    const float* br2   = (const float*)d_in[12];
    const float* att2  = (const float*)d_in[13];
    const float* bias2 = (const float*)d_in[14];
    float* out = (float*)d_out;

    // Workspace layout (liveness-overlapped, total 171,442,176 B):
    //   [0,        3.67MB)  knn [N][7] int32                       (live: all)
    //   [3.67MB,  70.78MB)  slotA: xl1|xr1 [N][64]x2 -> xl2 [N][128]
    //   [70.78MB, 87.56MB)  h1b [N][64] bf16  -> partial [2048][128] (after lin2)
    //   [87.56MB, 87.59MB)  wbf [8][256][8] bf16 (32 KB)
    //   [104.33, 171.44MB)  xr2 [N][128]
    char* ws = (char*)d_ws;
    int*            knn  = (int*)(ws + 0);
    float*          xl1  = (float*)(ws + 3670016);
    float*          xr1  = (float*)(ws + 37224448);
    unsigned short* h1b  = (unsigned short*)(ws + 70778880);
    unsigned short* wbf  = (unsigned short*)(ws + 87556096);
    float*          xl2  = (float*)(ws + 3670016);     // over dead xl1|xr1
    float*          xr2  = (float*)(ws + 104333312);
    float*          partial = (float*)(ws + 70778880); // over dead h1b

    knn_kernel<<<N_NODES / 4, 256, 0, stream>>>(pos, knn);
    lin1_kernel<<<(N_NODES * 16) / 256, 256, 0, stream>>>(x, Wl1, bl1, Wr1, br1, xl1, xr1);
    wprep_kernel<<<64, 256, 0, stream>>>(Wl2, Wr2, wbf);
    agg1_kernel<<<(N_NODES * 4) / 256, 256, 0, stream>>>(xl1, xr1, knn, att1, bias1, h1b);
    lin2_kernel<<<N_NODES / 16, 256, 0, stream>>>(h1b, wbf, bl2, br2, xl2, xr2);
    agg2_pool_kernel<<<N_NODES / 64, 256, 0, stream>>>(xl2, xr2, knn, att2, partial);
    pool2_kernel<<<B_GRAPHS, 128, 0, stream>>>(partial, bias2, out);
}

// Round 9
// 269.558 us; speedup vs baseline: 2.6335x; 1.0268x over previous
//
#include <hip/hip_runtime.h>
#include <hip/hip_bf16.h>

#define N_NODES 131072
#define B_GRAPHS 256
#define NPG 512
#define KNN 7
#define HEADS 4

using f4 = __attribute__((ext_vector_type(4))) float;
using short8 = __attribute__((ext_vector_type(8))) short;  // 8 bf16 (4 VGPRs)

__device__ __forceinline__ unsigned short f2bf(float f) {   // RNE f32->bf16
    unsigned u = __builtin_bit_cast(unsigned, f);
    u += 0x7FFFu + ((u >> 16) & 1u);
    return (unsigned short)(u >> 16);
}

// ---------------------------------------------------------------------------
// Kernel 1: cooperative wave-per-query kNN (K=7). (unchanged: VALUBusy 95%,
// occupancy 84% -- at its algorithmic issue roofline; revisit next round)
// ---------------------------------------------------------------------------
__global__ __launch_bounds__(256) void knn_kernel(const float* __restrict__ pos,
                                                  int* __restrict__ knn) {
    __shared__ float sp[NPG * 3];
    const int tid = threadIdx.x;
    const int lane = tid & 63;
    const size_t node = (size_t)blockIdx.x * 4 + (tid >> 6);
    const int g = (int)(node >> 9);
    const int q = (int)(node & 511);

    const float* p = pos + (size_t)g * NPG * 3;
    for (int i = tid; i < NPG * 3; i += 256) sp[i] = p[i];
    __syncthreads();

    const float qx = sp[q * 3 + 0];
    const float qy = sp[q * 3 + 1];
    const float qz = sp[q * 3 + 2];

    float d0, d1, d2_, d3, d4, d5, d6, d7;
    {
        float dd[8];
#pragma unroll
        for (int it = 0; it < 8; ++it) {
            const int c = (it << 6) | lane;
            const float dx = qx - sp[c * 3 + 0];
            const float dy = qy - sp[c * 3 + 1];
            const float dz = qz - sp[c * 3 + 2];
            float d = dx * dx + dy * dy + dz * dz;
            dd[it] = (c == q) ? 1e30f : d;
        }
        d0 = dd[0]; d1 = dd[1]; d2_ = dd[2]; d3 = dd[3];
        d4 = dd[4]; d5 = dd[5]; d6 = dd[6]; d7 = dd[7];
    }
    int t0 = 0, t1 = 1, t2 = 2, t3 = 3, t4 = 4, t5 = 5, t6 = 6, t7 = 7;

#define CE(da, ta, db, tb) { \
        const bool sw = db < da; \
        const float dmin = sw ? db : da; const float dmax = sw ? da : db; \
        const int   tmin = sw ? tb : ta; const int   tmax = sw ? ta : tb; \
        da = dmin; db = dmax; ta = tmin; tb = tmax; }
    CE(d0,t0,d1,t1) CE(d2_,t2,d3,t3) CE(d4,t4,d5,t5) CE(d6,t6,d7,t7)
    CE(d0,t0,d2_,t2) CE(d1,t1,d3,t3) CE(d4,t4,d6,t6) CE(d5,t5,d7,t7)
    CE(d1,t1,d2_,t2) CE(d5,t5,d6,t6)
    CE(d0,t0,d4,t4) CE(d1,t1,d5,t5) CE(d2_,t2,d6,t6) CE(d3,t3,d7,t7)
    CE(d2_,t2,d4,t4) CE(d3,t3,d5,t5)
    CE(d1,t1,d2_,t2) CE(d3,t3,d4,t4) CE(d5,t5,d6,t6)
#undef CE

    int myneigh = 0;
#pragma unroll
    for (int r = 0; r < KNN; ++r) {
        float m = d0;
        m = fminf(m, __shfl_xor(m, 1));
        m = fminf(m, __shfl_xor(m, 2));
        m = fminf(m, __shfl_xor(m, 4));
        m = fminf(m, __shfl_xor(m, 8));
        m = fminf(m, __shfl_xor(m, 16));
        m = fminf(m, __shfl_xor(m, 32));
        const unsigned long long b = __ballot(d0 == m);
        const int winlane = __ffsll((long long)b) - 1;
        const int cand = (t0 << 6) | lane;
        const int widx = __shfl(cand, winlane);
        if (lane == r) myneigh = widx;
        if (lane == winlane) {
            d0 = d1; d1 = d2_; d2_ = d3; d3 = d4; d4 = d5; d5 = d6; d6 = d7; d7 = 1e30f;
            t0 = t1; t1 = t2; t2 = t3; t3 = t4; t4 = t5; t5 = t6; t6 = t7;
        }
    }
    if (lane < KNN) knn[node * KNN + lane] = g * NPG + myneigh;
}

// ---------------------------------------------------------------------------
// Kernel 2: fused xl1 = x@Wl1+bl1, xr1 = x@Wr1+br1  ([N,10]@[10,64]).
// ---------------------------------------------------------------------------
__global__ __launch_bounds__(256) void lin1_kernel(const float* __restrict__ x,
                                                   const float* __restrict__ Wl,
                                                   const float* __restrict__ bl,
                                                   const float* __restrict__ Wr,
                                                   const float* __restrict__ br,
                                                   float* __restrict__ xl1,
                                                   float* __restrict__ xr1) {
    const int idx = blockIdx.x * 256 + threadIdx.x;   // N*16
    const int c4 = idx & 15;
    const size_t node = (size_t)(idx >> 4);
    const float* xrow = x + node * 10;
    f4 al = ((const f4*)bl)[c4];
    f4 ar = ((const f4*)br)[c4];
#pragma unroll
    for (int k = 0; k < 10; ++k) {
        const float xv = xrow[k];
        al += xv * ((const f4*)(Wl + k * 64))[c4];
        ar += xv * ((const f4*)(Wr + k * 64))[c4];
    }
    ((f4*)(xl1 + node * 64))[c4] = al;
    ((f4*)(xr1 + node * 64))[c4] = ar;
}

// ---------------------------------------------------------------------------
// Kernel 3: GATv2 layer-1 aggregation. One thread per (node, head), C=16.
// Writes h1 as bf16 (its only consumer is the MFMA lin2).
// ---------------------------------------------------------------------------
__global__ __launch_bounds__(256) void agg1_kernel(const float* __restrict__ xl,
                                                   const float* __restrict__ xr,
                                                   const int* __restrict__ knn,
                                                   const float* __restrict__ att,
                                                   const float* __restrict__ bias,
                                                   unsigned short* __restrict__ h1b) {
    const int idx = blockIdx.x * 256 + threadIdx.x;   // N*4
    const int h = idx & 3;
    const size_t node = (size_t)(idx >> 2);
    const int* nb = knn + node * KNN;
    int j[KNN];
#pragma unroll
    for (int k = 0; k < KNN; ++k) j[k] = nb[k];

    f4 xr4[4], at4[4];
    const f4* xrp = (const f4*)(xr + node * 64 + h * 16);
    const f4* atp = (const f4*)(att + h * 16);
#pragma unroll
    for (int i = 0; i < 4; ++i) { xr4[i] = xrp[i]; at4[i] = atp[i]; }

    float alpha[KNN];
#pragma unroll
    for (int k = 0; k < KNN; ++k) {
        const f4* xlp = (const f4*)(xl + (size_t)j[k] * 64 + h * 16);
        float s = 0.f;
#pragma unroll
        for (int i = 0; i < 4; ++i) {
            const f4 m = xlp[i] + xr4[i];
#pragma unroll
            for (int c = 0; c < 4; ++c) {
                float mm = m[c];
                mm = mm > 0.f ? mm : 0.2f * mm;   // leaky_relu(., 0.2)
                s += mm * at4[i][c];
            }
        }
        alpha[k] = s;
    }
    float amax = alpha[0];
#pragma unroll
    for (int k = 1; k < KNN; ++k) amax = fmaxf(amax, alpha[k]);
    float e[KNN];
    float denom = 0.f;
#pragma unroll
    for (int k = 0; k < KNN; ++k) { e[k] = expf(alpha[k] - amax); denom += e[k]; }
    const float rd = 1.f / denom;

    f4 o4[4];
#pragma unroll
    for (int i = 0; i < 4; ++i) o4[i] = 0.f;
#pragma unroll
    for (int k = 0; k < KNN; ++k) {
        const f4* xlp = (const f4*)(xl + (size_t)j[k] * 64 + h * 16);
#pragma unroll
        for (int i = 0; i < 4; ++i) o4[i] += e[k] * xlp[i];
    }
    const f4* bp = (const f4*)(bias + h * 16);
    short8 r0, r1;
#pragma unroll
    for (int i = 0; i < 4; ++i) {
        const f4 v = o4[i] * rd + bp[i];
#pragma unroll
        for (int c = 0; c < 4; ++c) {
            const unsigned short bv = f2bf(v[c]);
            const int e4 = i * 4 + c;
            if (e4 < 8) r0[e4] = (short)bv; else r1[e4 - 8] = (short)bv;
        }
    }
    short8* hp = (short8*)(h1b + node * 64 + h * 16);
    hp[0] = r0;
    hp[1] = r1;
}

// ---------------------------------------------------------------------------
// Kernel 4a: pack Wl2||Wr2 into bf16 MFMA B-fragment layout.
// ---------------------------------------------------------------------------
__global__ __launch_bounds__(256) void wprep_kernel(const float* __restrict__ Wl,
                                                    const float* __restrict__ Wr,
                                                    unsigned short* __restrict__ wbf) {
    const int t = blockIdx.x * 256 + threadIdx.x;   // 64*256 = 16384
    const int k = t >> 8;       // 0..63
    const int n = t & 255;      // 0..255
    const float v = (n < 128) ? Wl[k * 128 + n] : Wr[k * 128 + (n - 128)];
    wbf[((k >> 3) * 256 + n) * 8 + (k & 7)] = f2bf(v);
}

// ---------------------------------------------------------------------------
// Kernel 4b: lin2 via MFMA (verified round 8). 16 nodes x 256 cols per block.
// ---------------------------------------------------------------------------
__global__ __launch_bounds__(256) void lin2_kernel(const unsigned short* __restrict__ h1b,
                                                   const unsigned short* __restrict__ wbf,
                                                   const float* __restrict__ bl,
                                                   const float* __restrict__ br,
                                                   float* __restrict__ xl2,
                                                   float* __restrict__ xr2) {
    const int tid = threadIdx.x;
    const int lane = tid & 63;
    const int w = tid >> 6;
    const size_t node0 = (size_t)blockIdx.x * 16;
    const int lm = lane & 15, lk = lane >> 4;

    const short8* hp = (const short8*)h1b;
    const short8 a0 = hp[(node0 + lm) * 8 + lk];       // k = lk*8 .. +8
    const short8 a1 = hp[(node0 + lm) * 8 + lk + 4];   // k = 32 + lk*8 .. +8

    const short8* wp = (const short8*)wbf;
#pragma unroll
    for (int t = 0; t < 4; ++t) {
        const int col = w * 64 + t * 16 + lm;          // uniform half per wave
        const float bias = (col < 128) ? bl[col] : br[col - 128];
        f4 acc = {bias, bias, bias, bias};
        const short8 b0 = wp[lk * 256 + col];
        const short8 b1 = wp[(lk + 4) * 256 + col];
        acc = __builtin_amdgcn_mfma_f32_16x16x32_bf16(a0, b0, acc, 0, 0, 0);
        acc = __builtin_amdgcn_mfma_f32_16x16x32_bf16(a1, b1, acc, 0, 0, 0);
        float* dst = (col < 128) ? (xl2 + col) : (xr2 + (col - 128));
#pragma unroll
        for (int r = 0; r < 4; ++r)
            dst[(node0 + lk * 4 + r) * 128] = acc[r];
    }
}

// ---------------------------------------------------------------------------
// Kernel 5: GATv2 layer-2 aggregation + pooling, restructured.
// One thread per (node, head, half): 16 channels (4 f4). 8 lanes per node ->
// 512B coalesced gathers. Block = 256 thr = 4 waves = 32 nodes. Pool via
// 3-step shfl_xor butterfly over the wave's 8 nodes; one 128-ch partial per
// wave written straight to global. No LDS, no syncthreads.
// ---------------------------------------------------------------------------
__global__ __launch_bounds__(256) void agg2_pool_kernel(const float* __restrict__ xl,
                                                        const float* __restrict__ xr,
                                                        const int* __restrict__ knn,
                                                        const float* __restrict__ att,
                                                        float* __restrict__ partial) {
    const int tid = threadIdx.x;
    const int lane = tid & 63;
    const int wv = tid >> 6;
    const int n8 = lane >> 3;            // node within wave (0..7)
    const int h = (lane >> 1) & 3;       // head
    const int half = lane & 1;           // channel half
    const size_t node = (size_t)blockIdx.x * 32 + wv * 8 + n8;
    const int co = h * 32 + half * 16;   // this thread's 16 channels

    const int* nb = knn + node * KNN;
    int j[KNN];
#pragma unroll
    for (int k = 0; k < KNN; ++k) j[k] = nb[k];

    f4 xr4[4], at4[4];
    const f4* xrp = (const f4*)(xr + node * 128 + co);
    const f4* atp = (const f4*)(att + co);
#pragma unroll
    for (int i = 0; i < 4; ++i) { xr4[i] = xrp[i]; at4[i] = atp[i]; }

    float alpha[KNN];
#pragma unroll
    for (int k = 0; k < KNN; ++k) {
        const f4* xlp = (const f4*)(xl + (size_t)j[k] * 128 + co);
        float s = 0.f;
#pragma unroll
        for (int i = 0; i < 4; ++i) {
            const f4 m = xlp[i] + xr4[i];
#pragma unroll
            for (int c = 0; c < 4; ++c) {
                float mm = m[c];
                mm = mm > 0.f ? mm : 0.2f * mm;
                s += mm * at4[i][c];
            }
        }
        alpha[k] = s + __shfl_xor(s, 1);   // combine the two channel-halves
    }
    float amax = alpha[0];
#pragma unroll
    for (int k = 1; k < KNN; ++k) amax = fmaxf(amax, alpha[k]);
    float e[KNN];
    float denom = 0.f;
#pragma unroll
    for (int k = 0; k < KNN; ++k) { e[k] = expf(alpha[k] - amax); denom += e[k]; }
    const float rd = 1.f / denom;

    f4 o4[4];
#pragma unroll
    for (int i = 0; i < 4; ++i) o4[i] = 0.f;
#pragma unroll
    for (int k = 0; k < KNN; ++k) {
        const f4* xlp = (const f4*)(xl + (size_t)j[k] * 128 + co);
#pragma unroll
        for (int i = 0; i < 4; ++i) o4[i] += e[k] * xlp[i];
    }
#pragma unroll
    for (int i = 0; i < 4; ++i) o4[i] *= rd;

    // butterfly-reduce over the 8 nodes in this wave (lanes differing in bits 3..5)
#pragma unroll
    for (int m = 8; m <= 32; m <<= 1) {
#pragma unroll
        for (int i = 0; i < 4; ++i) {
#pragma unroll
            for (int c = 0; c < 4; ++c) o4[i][c] += __shfl_xor(o4[i][c], m);
        }
    }
    if (n8 == 0) {   // lanes 0..7 cover all (h,half): one 128-ch partial per wave
        f4* pp = (f4*)(partial + ((size_t)blockIdx.x * 4 + wv) * 128 + co);
#pragma unroll
        for (int i = 0; i < 4; ++i) pp[i] = o4[i];
    }
}

// ---------------------------------------------------------------------------
// Kernel 6: stage-2 pool. One block per graph; combines the 64 wave partials
// (16 blocks x 4 waves), divides by NPG, adds bias2.
// ---------------------------------------------------------------------------
__global__ __launch_bounds__(128) void pool2_kernel(const float* __restrict__ partial,
                                                    const float* __restrict__ bias,
                                                    float* __restrict__ out) {
    const int g = blockIdx.x;
    const int c = threadIdx.x;
    float s = 0.f;
#pragma unroll
    for (int b = 0; b < 64; ++b) s += partial[(size_t)(g * 64 + b) * 128 + c];
    out[g * 128 + c] = s * (1.f / 512.f) + bias[c];
}

extern "C" void kernel_launch(void* const* d_in, const int* in_sizes, int n_in,
                              void* d_out, int out_size, void* d_ws, size_t ws_size,
                              hipStream_t stream) {
    const float* pos   = (const float*)d_in[0];
    const float* x     = (const float*)d_in[1];
    const float* Wl1   = (const float*)d_in[3];
    const float* bl1   = (const float*)d_in[4];
    const float* Wr1   = (const float*)d_in[5];
    const float* br1   = (const float*)d_in[6];
    const float* att1  = (const float*)d_in[7];
    const float* bias1 = (const float*)d_in[8];
    const float* Wl2   = (const float*)d_in[9];
    const float* bl2   = (const float*)d_in[10];
    const float* Wr2   = (const float*)d_in[11];
    const float* br2   = (const float*)d_in[12];
    const float* att2  = (const float*)d_in[13];
    const float* bias2 = (const float*)d_in[14];
    float* out = (float*)d_out;

    // Workspace layout (liveness-overlapped, total 171,442,176 B):
    //   [0,        3.67MB)  knn [N][7] int32                       (live: all)
    //   [3.67MB,  70.78MB)  slotA: xl1|xr1 [N][64]x2 -> xl2 [N][128]
    //   [70.78MB, 87.56MB)  h1b [N][64] bf16 -> partial [16384][128] (8.4MB, after lin2)
    //   [87.56MB, 87.59MB)  wbf [8][256][8] bf16 (32 KB)
    //   [104.33, 171.44MB)  xr2 [N][128]
    char* ws = (char*)d_ws;
    int*            knn  = (int*)(ws + 0);
    float*          xl1  = (float*)(ws + 3670016);
    float*          xr1  = (float*)(ws + 37224448);
    unsigned short* h1b  = (unsigned short*)(ws + 70778880);
    unsigned short* wbf  = (unsigned short*)(ws + 87556096);
    float*          xl2  = (float*)(ws + 3670016);     // over dead xl1|xr1
    float*          xr2  = (float*)(ws + 104333312);
    float*          partial = (float*)(ws + 70778880); // over dead h1b

    knn_kernel<<<N_NODES / 4, 256, 0, stream>>>(pos, knn);
    lin1_kernel<<<(N_NODES * 16) / 256, 256, 0, stream>>>(x, Wl1, bl1, Wr1, br1, xl1, xr1);
    wprep_kernel<<<64, 256, 0, stream>>>(Wl2, Wr2, wbf);
    agg1_kernel<<<(N_NODES * 4) / 256, 256, 0, stream>>>(xl1, xr1, knn, att1, bias1, h1b);
    lin2_kernel<<<N_NODES / 16, 256, 0, stream>>>(h1b, wbf, bl2, br2, xl2, xr2);
    agg2_pool_kernel<<<N_NODES / 32, 256, 0, stream>>>(xl2, xr2, knn, att2, partial);
    pool2_kernel<<<B_GRAPHS, 128, 0, stream>>>(partial, bias2, out);
}

// Round 10
// 179.847 us; speedup vs baseline: 3.9472x; 1.4988x over previous
//
#include <hip/hip_runtime.h>
#include <hip/hip_bf16.h>

#define N_NODES 131072
#define B_GRAPHS 256
#define NPG 512
#define KNN 7
#define HEADS 4

using f4 = __attribute__((ext_vector_type(4))) float;
using short8 = __attribute__((ext_vector_type(8))) short;  // 8 bf16 (4 VGPRs)

__device__ __forceinline__ unsigned short f2bf(float f) {   // RNE f32->bf16
    unsigned u = __builtin_bit_cast(unsigned, f);
    u += 0x7FFFu + ((u >> 16) & 1u);
    return (unsigned short)(u >> 16);
}

__device__ __forceinline__ void s8_to_f(const short8 v, f4* out) {  // 8 bf16 -> 2 f4
#pragma unroll
    for (int i = 0; i < 8; ++i) {
        const unsigned u = ((unsigned)(unsigned short)v[i]) << 16;
        out[i >> 2][i & 3] = __builtin_bit_cast(float, u);
    }
}

// ---------------------------------------------------------------------------
// Kernel 1: thread-per-query kNN with packed-key branchless top-7.
// key = (bits(d2) & ~0x1FF) | j : positive-float bits are order-isomorphic to
// unsigned; low 9 bits carry the candidate index (lower index wins ties, like
// top_k). Insert = 1 umin + 6x(umin+umax) = 13 VALU, no branches, no scratch.
// Block = 256 thr = 256 queries (2 blocks/graph); positions staged as f4.
// ---------------------------------------------------------------------------
__global__ __launch_bounds__(256) void knn_kernel(const float* __restrict__ pos,
                                                  int* __restrict__ knn) {
    __shared__ f4 sp[NPG];
    const int tid = threadIdx.x;
    const int g = blockIdx.x >> 1;
    const int q = ((blockIdx.x & 1) << 8) | tid;   // local query 0..511

    const float* p = pos + (size_t)g * NPG * 3;
    for (int i = tid; i < NPG; i += 256) {
        f4 v; v[0] = p[i * 3 + 0]; v[1] = p[i * 3 + 1]; v[2] = p[i * 3 + 2]; v[3] = 0.f;
        sp[i] = v;
    }
    __syncthreads();

    const f4 qp = sp[q];
    unsigned b0 = ~0u, b1 = ~0u, b2 = ~0u, b3 = ~0u, b4 = ~0u, b5 = ~0u, b6 = ~0u;

#define CEU(a, b) { const unsigned _mn = min(a, b); b = max(a, b); a = _mn; }
#pragma unroll 4
    for (int j = 0; j < NPG; ++j) {
        const f4 c = sp[j];                         // wave-uniform -> broadcast
        const float dx = qp[0] - c[0];
        const float dy = qp[1] - c[1];
        const float dz = qp[2] - c[2];
        const float d2 = dx * dx + dy * dy + dz * dz;
        unsigned key = (__builtin_bit_cast(unsigned, d2) & 0xFFFFFE00u) | (unsigned)j;
        key = (j == q) ? 0xFFFFFFFFu : key;         // no self-loop
        b6 = min(b6, key);
        CEU(b5, b6) CEU(b4, b5) CEU(b3, b4) CEU(b2, b3) CEU(b1, b2) CEU(b0, b1)
    }
#undef CEU
    const int base = (g * NPG + q) * KNN;
    const int off = g * NPG;
    knn[base + 0] = off + (int)(b0 & 0x1FFu);
    knn[base + 1] = off + (int)(b1 & 0x1FFu);
    knn[base + 2] = off + (int)(b2 & 0x1FFu);
    knn[base + 3] = off + (int)(b3 & 0x1FFu);
    knn[base + 4] = off + (int)(b4 & 0x1FFu);
    knn[base + 5] = off + (int)(b5 & 0x1FFu);
    knn[base + 6] = off + (int)(b6 & 0x1FFu);
}

// ---------------------------------------------------------------------------
// Kernel 2: fused xl1 = x@Wl1+bl1, xr1 = x@Wr1+br1  ([N,10]@[10,64]).
// ---------------------------------------------------------------------------
__global__ __launch_bounds__(256) void lin1_kernel(const float* __restrict__ x,
                                                   const float* __restrict__ Wl,
                                                   const float* __restrict__ bl,
                                                   const float* __restrict__ Wr,
                                                   const float* __restrict__ br,
                                                   float* __restrict__ xl1,
                                                   float* __restrict__ xr1) {
    const int idx = blockIdx.x * 256 + threadIdx.x;   // N*16
    const int c4 = idx & 15;
    const size_t node = (size_t)(idx >> 4);
    const float* xrow = x + node * 10;
    f4 al = ((const f4*)bl)[c4];
    f4 ar = ((const f4*)br)[c4];
#pragma unroll
    for (int k = 0; k < 10; ++k) {
        const float xv = xrow[k];
        al += xv * ((const f4*)(Wl + k * 64))[c4];
        ar += xv * ((const f4*)(Wr + k * 64))[c4];
    }
    ((f4*)(xl1 + node * 64))[c4] = al;
    ((f4*)(xr1 + node * 64))[c4] = ar;
}

// ---------------------------------------------------------------------------
// Kernel 3: GATv2 layer-1 aggregation. One thread per (node, head), C=16.
// XCD-swizzled: all 8 blocks of a graph land on one XCD (L2 locality).
// Writes h1 as bf16 (consumer is the MFMA lin2).
// ---------------------------------------------------------------------------
__global__ __launch_bounds__(256) void agg1_kernel(const float* __restrict__ xl,
                                                   const float* __restrict__ xr,
                                                   const int* __restrict__ knn,
                                                   const float* __restrict__ att,
                                                   const float* __restrict__ bias,
                                                   unsigned short* __restrict__ h1b) {
    // 2048 blocks; XCD x = bid&7 gets graphs [x*32,(x+1)*32), 8 blocks/graph
    const int x = blockIdx.x & 7;
    const int i = blockIdx.x >> 3;            // 0..255
    const int graph = x * 32 + (i >> 3);
    const int sub = i & 7;
    const int tid = threadIdx.x;
    const int h = tid & 3;
    const size_t node = (size_t)graph * NPG + sub * 64 + (tid >> 2);

    const int* nb = knn + node * KNN;
    int j[KNN];
#pragma unroll
    for (int k = 0; k < KNN; ++k) j[k] = nb[k];

    f4 xr4[4], at4[4];
    const f4* xrp = (const f4*)(xr + node * 64 + h * 16);
    const f4* atp = (const f4*)(att + h * 16);
#pragma unroll
    for (int i2 = 0; i2 < 4; ++i2) { xr4[i2] = xrp[i2]; at4[i2] = atp[i2]; }

    float alpha[KNN];
#pragma unroll
    for (int k = 0; k < KNN; ++k) {
        const f4* xlp = (const f4*)(xl + (size_t)j[k] * 64 + h * 16);
        float s = 0.f;
#pragma unroll
        for (int i2 = 0; i2 < 4; ++i2) {
            const f4 m = xlp[i2] + xr4[i2];
#pragma unroll
            for (int c = 0; c < 4; ++c) {
                float mm = m[c];
                mm = mm > 0.f ? mm : 0.2f * mm;   // leaky_relu(., 0.2)
                s += mm * at4[i2][c];
            }
        }
        alpha[k] = s;
    }
    float amax = alpha[0];
#pragma unroll
    for (int k = 1; k < KNN; ++k) amax = fmaxf(amax, alpha[k]);
    float e[KNN];
    float denom = 0.f;
#pragma unroll
    for (int k = 0; k < KNN; ++k) { e[k] = expf(alpha[k] - amax); denom += e[k]; }
    const float rd = 1.f / denom;

    f4 o4[4];
#pragma unroll
    for (int i2 = 0; i2 < 4; ++i2) o4[i2] = 0.f;
#pragma unroll
    for (int k = 0; k < KNN; ++k) {
        const f4* xlp = (const f4*)(xl + (size_t)j[k] * 64 + h * 16);
#pragma unroll
        for (int i2 = 0; i2 < 4; ++i2) o4[i2] += e[k] * xlp[i2];
    }
    const f4* bp = (const f4*)(bias + h * 16);
    short8 r0, r1;
#pragma unroll
    for (int i2 = 0; i2 < 4; ++i2) {
        const f4 v = o4[i2] * rd + bp[i2];
#pragma unroll
        for (int c = 0; c < 4; ++c) {
            const unsigned short bv = f2bf(v[c]);
            const int e4 = i2 * 4 + c;
            if (e4 < 8) r0[e4] = (short)bv; else r1[e4 - 8] = (short)bv;
        }
    }
    short8* hp = (short8*)(h1b + node * 64 + h * 16);
    hp[0] = r0;
    hp[1] = r1;
}

// ---------------------------------------------------------------------------
// Kernel 4a: pack Wl2||Wr2 into bf16 MFMA B-fragment layout.
// ---------------------------------------------------------------------------
__global__ __launch_bounds__(256) void wprep_kernel(const float* __restrict__ Wl,
                                                    const float* __restrict__ Wr,
                                                    unsigned short* __restrict__ wbf) {
    const int t = blockIdx.x * 256 + threadIdx.x;   // 64*256 = 16384
    const int k = t >> 8;
    const int n = t & 255;
    const float v = (n < 128) ? Wl[k * 128 + n] : Wr[k * 128 + (n - 128)];
    wbf[((k >> 3) * 256 + n) * 8 + (k & 7)] = f2bf(v);
}

// ---------------------------------------------------------------------------
// Kernel 4b: lin2 via MFMA (mapping verified round 8). Outputs bf16 now.
// ---------------------------------------------------------------------------
__global__ __launch_bounds__(256) void lin2_kernel(const unsigned short* __restrict__ h1b,
                                                   const unsigned short* __restrict__ wbf,
                                                   const float* __restrict__ bl,
                                                   const float* __restrict__ br,
                                                   unsigned short* __restrict__ xl2b,
                                                   unsigned short* __restrict__ xr2b) {
    const int tid = threadIdx.x;
    const int lane = tid & 63;
    const int w = tid >> 6;
    const size_t node0 = (size_t)blockIdx.x * 16;
    const int lm = lane & 15, lk = lane >> 4;

    const short8* hp = (const short8*)h1b;
    const short8 a0 = hp[(node0 + lm) * 8 + lk];
    const short8 a1 = hp[(node0 + lm) * 8 + lk + 4];

    const short8* wp = (const short8*)wbf;
#pragma unroll
    for (int t = 0; t < 4; ++t) {
        const int col = w * 64 + t * 16 + lm;
        const float bias = (col < 128) ? bl[col] : br[col - 128];
        f4 acc = {bias, bias, bias, bias};
        const short8 b0 = wp[lk * 256 + col];
        const short8 b1 = wp[(lk + 4) * 256 + col];
        acc = __builtin_amdgcn_mfma_f32_16x16x32_bf16(a0, b0, acc, 0, 0, 0);
        acc = __builtin_amdgcn_mfma_f32_16x16x32_bf16(a1, b1, acc, 0, 0, 0);
        unsigned short* dst = (col < 128) ? (xl2b + col) : (xr2b + (col - 128));
#pragma unroll
        for (int r = 0; r < 4; ++r)
            dst[(node0 + lk * 4 + r) * 128] = f2bf(acc[r]);
    }
}

// ---------------------------------------------------------------------------
// Kernel 5: GATv2 layer-2 aggregation + pooling. bf16 gathers, XCD-swizzled.
// One thread per (node, head, half): 16 channels. Wave = 8 nodes; butterfly
// pool reduce; partial indexed by WORK (graph,sub), not blockIdx.
// ---------------------------------------------------------------------------
__global__ __launch_bounds__(256) void agg2_pool_kernel(const unsigned short* __restrict__ xl2b,
                                                        const unsigned short* __restrict__ xr2b,
                                                        const int* __restrict__ knn,
                                                        const float* __restrict__ att,
                                                        float* __restrict__ partial) {
    // 4096 blocks; XCD x = bid&7 gets graphs [x*32,(x+1)*32), 16 blocks/graph
    const int x = blockIdx.x & 7;
    const int i = blockIdx.x >> 3;            // 0..511
    const int graph = x * 32 + (i >> 4);
    const int sub = i & 15;                   // 32-node chunk within graph
    const int tid = threadIdx.x;
    const int lane = tid & 63;
    const int wv = tid >> 6;
    const int n8 = lane >> 3;
    const int h = (lane >> 1) & 3;
    const int half = lane & 1;
    const size_t node = (size_t)graph * NPG + sub * 32 + wv * 8 + n8;
    const int co = h * 32 + half * 16;

    const int* nb = knn + node * KNN;
    int j[KNN];
#pragma unroll
    for (int k = 0; k < KNN; ++k) j[k] = nb[k];

    f4 xr4[4], at4[4];
    {
        const short8* xrp = (const short8*)(xr2b + node * 128 + co);
        s8_to_f(xrp[0], &xr4[0]);
        s8_to_f(xrp[1], &xr4[2]);
        const f4* atp = (const f4*)(att + co);
#pragma unroll
        for (int i2 = 0; i2 < 4; ++i2) at4[i2] = atp[i2];
    }

    float alpha[KNN];
#pragma unroll
    for (int k = 0; k < KNN; ++k) {
        const short8* xlp = (const short8*)(xl2b + (size_t)j[k] * 128 + co);
        f4 xlv[4];
        s8_to_f(xlp[0], &xlv[0]);
        s8_to_f(xlp[1], &xlv[2]);
        float s = 0.f;
#pragma unroll
        for (int i2 = 0; i2 < 4; ++i2) {
            const f4 m = xlv[i2] + xr4[i2];
#pragma unroll
            for (int c = 0; c < 4; ++c) {
                float mm = m[c];
                mm = mm > 0.f ? mm : 0.2f * mm;
                s += mm * at4[i2][c];
            }
        }
        alpha[k] = s + __shfl_xor(s, 1);   // combine the two channel-halves
    }
    float amax = alpha[0];
#pragma unroll
    for (int k = 1; k < KNN; ++k) amax = fmaxf(amax, alpha[k]);
    float e[KNN];
    float denom = 0.f;
#pragma unroll
    for (int k = 0; k < KNN; ++k) { e[k] = expf(alpha[k] - amax); denom += e[k]; }
    const float rd = 1.f / denom;

    f4 o4[4];
#pragma unroll
    for (int i2 = 0; i2 < 4; ++i2) o4[i2] = 0.f;
#pragma unroll
    for (int k = 0; k < KNN; ++k) {
        const short8* xlp = (const short8*)(xl2b + (size_t)j[k] * 128 + co);
        f4 xlv[4];
        s8_to_f(xlp[0], &xlv[0]);
        s8_to_f(xlp[1], &xlv[2]);
#pragma unroll
        for (int i2 = 0; i2 < 4; ++i2) o4[i2] += e[k] * xlv[i2];
    }
#pragma unroll
    for (int i2 = 0; i2 < 4; ++i2) o4[i2] *= rd;

    // butterfly-reduce over the 8 nodes in this wave
#pragma unroll
    for (int m = 8; m <= 32; m <<= 1) {
#pragma unroll
        for (int i2 = 0; i2 < 4; ++i2) {
#pragma unroll
            for (int c = 0; c < 4; ++c) o4[i2][c] += __shfl_xor(o4[i2][c], m);
        }
    }
    if (n8 == 0) {
        // partial slot by WORK coordinates: graph*16 blocks-equivalent + sub
        f4* pp = (f4*)(partial + ((size_t)(graph * 16 + sub) * 4 + wv) * 128 + co);
#pragma unroll
        for (int i2 = 0; i2 < 4; ++i2) pp[i2] = o4[i2];
    }
}

// ---------------------------------------------------------------------------
// Kernel 6: stage-2 pool. One block per graph; 64 partials, /NPG, +bias2.
// ---------------------------------------------------------------------------
__global__ __launch_bounds__(128) void pool2_kernel(const float* __restrict__ partial,
                                                    const float* __restrict__ bias,
                                                    float* __restrict__ out) {
    const int g = blockIdx.x;
    const int c = threadIdx.x;
    float s = 0.f;
#pragma unroll
    for (int b = 0; b < 64; ++b) s += partial[(size_t)(g * 64 + b) * 128 + c];
    out[g * 128 + c] = s * (1.f / 512.f) + bias[c];
}

extern "C" void kernel_launch(void* const* d_in, const int* in_sizes, int n_in,
                              void* d_out, int out_size, void* d_ws, size_t ws_size,
                              hipStream_t stream) {
    const float* pos   = (const float*)d_in[0];
    const float* x     = (const float*)d_in[1];
    const float* Wl1   = (const float*)d_in[3];
    const float* bl1   = (const float*)d_in[4];
    const float* Wr1   = (const float*)d_in[5];
    const float* br1   = (const float*)d_in[6];
    const float* att1  = (const float*)d_in[7];
    const float* bias1 = (const float*)d_in[8];
    const float* Wl2   = (const float*)d_in[9];
    const float* bl2   = (const float*)d_in[10];
    const float* Wr2   = (const float*)d_in[11];
    const float* br2   = (const float*)d_in[12];
    const float* att2  = (const float*)d_in[13];
    const float* bias2 = (const float*)d_in[14];
    float* out = (float*)d_out;

    // Workspace layout (liveness-overlapped):
    //   [0,        3.67MB)  knn [N][7] int32                     (live: all)
    //   [3670016,  )        xl1 f32 [N][64]   (dead after agg1)
    //   [37224448, )        xr1 f32 [N][64]   (dead after agg1)
    //   [70778880, )        h1b bf16 [N][64]  (dead after lin2) -> partial [16384][128] f32
    //   [87556096, )        wbf bf16 32KB
    //   [88080384, )        xl2b bf16 [N][128] (33.5MB)
    //   [121634816,)        xr2b bf16 [N][128] (33.5MB)
    char* ws = (char*)d_ws;
    int*            knn  = (int*)(ws + 0);
    float*          xl1  = (float*)(ws + 3670016);
    float*          xr1  = (float*)(ws + 37224448);
    unsigned short* h1b  = (unsigned short*)(ws + 70778880);
    unsigned short* wbf  = (unsigned short*)(ws + 87556096);
    unsigned short* xl2b = (unsigned short*)(ws + 88080384);
    unsigned short* xr2b = (unsigned short*)(ws + 121634816);
    float*          partial = (float*)(ws + 70778880); // over dead h1b

    knn_kernel<<<N_NODES / 256, 256, 0, stream>>>(pos, knn);
    lin1_kernel<<<(N_NODES * 16) / 256, 256, 0, stream>>>(x, Wl1, bl1, Wr1, br1, xl1, xr1);
    wprep_kernel<<<64, 256, 0, stream>>>(Wl2, Wr2, wbf);
    agg1_kernel<<<(N_NODES * 4) / 256, 256, 0, stream>>>(xl1, xr1, knn, att1, bias1, h1b);
    lin2_kernel<<<N_NODES / 16, 256, 0, stream>>>(h1b, wbf, bl2, br2, xl2b, xr2b);
    agg2_pool_kernel<<<N_NODES / 32, 256, 0, stream>>>(xl2b, xr2b, knn, att2, partial);
    pool2_kernel<<<B_GRAPHS, 128, 0, stream>>>(partial, bias2, out);
}

// Round 11
// 167.507 us; speedup vs baseline: 4.2379x; 1.0737x over previous
//
#include <hip/hip_runtime.h>
#include <hip/hip_bf16.h>

#define N_NODES 131072
#define B_GRAPHS 256
#define NPG 512
#define KNN 7
#define HEADS 4

using f4 = __attribute__((ext_vector_type(4))) float;
using short8 = __attribute__((ext_vector_type(8))) short;  // 8 bf16 (4 VGPRs)

__device__ __forceinline__ unsigned short f2bf(float f) {   // RNE f32->bf16
    unsigned u = __builtin_bit_cast(unsigned, f);
    u += 0x7FFFu + ((u >> 16) & 1u);
    return (unsigned short)(u >> 16);
}

__device__ __forceinline__ void s8_to_f(const short8 v, f4* out) {  // 8 bf16 -> 2 f4
#pragma unroll
    for (int i = 0; i < 8; ++i) {
        const unsigned u = ((unsigned)(unsigned short)v[i]) << 16;
        out[i >> 2][i & 3] = __builtin_bit_cast(float, u);
    }
}

// prefix-insert of key into ascending top-7 (b[0..6]); depth-2, 13 min/max
#define INS7(B, KEY) { \
    const unsigned _k = (KEY); \
    const unsigned n0 = min(B[0], _k); \
    const unsigned n1 = max(B[0], min(B[1], _k)); \
    const unsigned n2 = max(B[1], min(B[2], _k)); \
    const unsigned n3 = max(B[2], min(B[3], _k)); \
    const unsigned n4 = max(B[3], min(B[4], _k)); \
    const unsigned n5 = max(B[4], min(B[5], _k)); \
    const unsigned n6 = max(B[5], min(B[6], _k)); \
    B[0]=n0; B[1]=n1; B[2]=n2; B[3]=n3; B[4]=n4; B[5]=n5; B[6]=n6; }

// ---------------------------------------------------------------------------
// Kernel 1: kNN, chunk-split within block. Block = 512 thr: waves 0-3 scan
// candidates [0,256) and waves 4-7 scan [256,512) for the same 256 queries.
// Packed keys: (bits(d2) & ~0x1FF) | j  (order-isomorphic for positive
// floats; low 9 bits = index, lower index wins ties like stable top_k).
// Merge of the two partial top-7 lists via LDS (stride-7 -> conflict-free).
// ---------------------------------------------------------------------------
__global__ __launch_bounds__(512) void knn_kernel(const float* __restrict__ pos,
                                                  int* __restrict__ knn) {
    __shared__ f4 sp[NPG];
    __shared__ unsigned mk[256 * 7];
    const int tid = threadIdx.x;
    const int g = blockIdx.x >> 1;
    const int qh = blockIdx.x & 1;
    const int ch = tid >> 8;                 // candidate chunk (0/1)
    const int q = (qh << 8) | (tid & 255);   // local query index

    const float* p = pos + (size_t)g * NPG * 3;
    {
        f4 v; v[0] = p[tid * 3 + 0]; v[1] = p[tid * 3 + 1]; v[2] = p[tid * 3 + 2]; v[3] = 0.f;
        sp[tid] = v;
    }
    __syncthreads();

    const f4 qp = sp[q];
    unsigned b[7];
#pragma unroll
    for (int i = 0; i < 7; ++i) b[i] = 0xFFFFFFFFu;

    const int j0 = ch << 8;
#pragma unroll 8
    for (int j = 0; j < 256; ++j) {
        const int jj = j0 + j;                  // scalar (wave-uniform)
        const f4 c = sp[jj];                    // LDS broadcast
        const float dx = qp[0] - c[0];
        const float dy = qp[1] - c[1];
        const float dz = qp[2] - c[2];
        const float d2 = dx * dx + dy * dy + dz * dz;
        unsigned key = (__builtin_bit_cast(unsigned, d2) & 0xFFFFFE00u) | (unsigned)jj;
        key = (jj == q) ? 0xFFFFFFFFu : key;    // no self-loop
        INS7(b, key)
    }

    if (ch == 1) {
        unsigned* m = &mk[(tid & 255) * 7];
#pragma unroll
        for (int i = 0; i < 7; ++i) m[i] = b[i];
    }
    __syncthreads();
    if (ch == 0) {
        const unsigned* m = &mk[tid * 7];
#pragma unroll
        for (int i = 0; i < 7; ++i) INS7(b, m[i])
        const int base = (g * NPG + q) * KNN;
        const int off = g * NPG;
#pragma unroll
        for (int i = 0; i < 7; ++i) knn[base + i] = off + (int)(b[i] & 0x1FFu);
    }
}
#undef INS7

// ---------------------------------------------------------------------------
// Kernel 2: fused lin1. xl1 -> bf16 (gathered 14x by agg1), xr1 stays f32
// (read once, coalesced -- quantizing it buys nothing).
// ---------------------------------------------------------------------------
__global__ __launch_bounds__(256) void lin1_kernel(const float* __restrict__ x,
                                                   const float* __restrict__ Wl,
                                                   const float* __restrict__ bl,
                                                   const float* __restrict__ Wr,
                                                   const float* __restrict__ br,
                                                   unsigned short* __restrict__ xl1b,
                                                   float* __restrict__ xr1) {
    const int idx = blockIdx.x * 256 + threadIdx.x;   // N*16
    const int c4 = idx & 15;
    const size_t node = (size_t)(idx >> 4);
    const float* xrow = x + node * 10;
    f4 al = ((const f4*)bl)[c4];
    f4 ar = ((const f4*)br)[c4];
#pragma unroll
    for (int k = 0; k < 10; ++k) {
        const float xv = xrow[k];
        al += xv * ((const f4*)(Wl + k * 64))[c4];
        ar += xv * ((const f4*)(Wr + k * 64))[c4];
    }
    uint2 pk;
    pk.x = (unsigned)f2bf(al[0]) | ((unsigned)f2bf(al[1]) << 16);
    pk.y = (unsigned)f2bf(al[2]) | ((unsigned)f2bf(al[3]) << 16);
    ((uint2*)xl1b)[node * 16 + c4] = pk;
    ((f4*)(xr1 + node * 64))[c4] = ar;
}

// ---------------------------------------------------------------------------
// Kernel 3: GATv2 layer-1 aggregation. bf16 xl gathers, f32 xr/compute.
// XCD-swizzled. Writes h1 as bf16.
// ---------------------------------------------------------------------------
__global__ __launch_bounds__(256) void agg1_kernel(const unsigned short* __restrict__ xl1b,
                                                   const float* __restrict__ xr,
                                                   const int* __restrict__ knn,
                                                   const float* __restrict__ att,
                                                   const float* __restrict__ bias,
                                                   unsigned short* __restrict__ h1b) {
    const int x = blockIdx.x & 7;
    const int i = blockIdx.x >> 3;
    const int graph = x * 32 + (i >> 3);
    const int sub = i & 7;
    const int tid = threadIdx.x;
    const int h = tid & 3;
    const size_t node = (size_t)graph * NPG + sub * 64 + (tid >> 2);

    const int* nb = knn + node * KNN;
    int j[KNN];
#pragma unroll
    for (int k = 0; k < KNN; ++k) j[k] = nb[k];

    f4 xr4[4], at4[4];
    const f4* xrp = (const f4*)(xr + node * 64 + h * 16);
    const f4* atp = (const f4*)(att + h * 16);
#pragma unroll
    for (int i2 = 0; i2 < 4; ++i2) { xr4[i2] = xrp[i2]; at4[i2] = atp[i2]; }

    float alpha[KNN];
#pragma unroll
    for (int k = 0; k < KNN; ++k) {
        const short8* xlp = (const short8*)(xl1b + (size_t)j[k] * 64 + h * 16);
        f4 xlv[4];
        s8_to_f(xlp[0], &xlv[0]);
        s8_to_f(xlp[1], &xlv[2]);
        float s = 0.f;
#pragma unroll
        for (int i2 = 0; i2 < 4; ++i2) {
            const f4 m = xlv[i2] + xr4[i2];
#pragma unroll
            for (int c = 0; c < 4; ++c) {
                float mm = m[c];
                mm = mm > 0.f ? mm : 0.2f * mm;   // leaky_relu(., 0.2)
                s += mm * at4[i2][c];
            }
        }
        alpha[k] = s;
    }
    float amax = alpha[0];
#pragma unroll
    for (int k = 1; k < KNN; ++k) amax = fmaxf(amax, alpha[k]);
    float e[KNN];
    float denom = 0.f;
#pragma unroll
    for (int k = 0; k < KNN; ++k) { e[k] = expf(alpha[k] - amax); denom += e[k]; }
    const float rd = 1.f / denom;

    f4 o4[4];
#pragma unroll
    for (int i2 = 0; i2 < 4; ++i2) o4[i2] = 0.f;
#pragma unroll
    for (int k = 0; k < KNN; ++k) {
        const short8* xlp = (const short8*)(xl1b + (size_t)j[k] * 64 + h * 16);
        f4 xlv[4];
        s8_to_f(xlp[0], &xlv[0]);
        s8_to_f(xlp[1], &xlv[2]);
#pragma unroll
        for (int i2 = 0; i2 < 4; ++i2) o4[i2] += e[k] * xlv[i2];
    }
    const f4* bp = (const f4*)(bias + h * 16);
    short8 r0, r1;
#pragma unroll
    for (int i2 = 0; i2 < 4; ++i2) {
        const f4 v = o4[i2] * rd + bp[i2];
#pragma unroll
        for (int c = 0; c < 4; ++c) {
            const unsigned short bv = f2bf(v[c]);
            const int e4 = i2 * 4 + c;
            if (e4 < 8) r0[e4] = (short)bv; else r1[e4 - 8] = (short)bv;
        }
    }
    short8* hp = (short8*)(h1b + node * 64 + h * 16);
    hp[0] = r0;
    hp[1] = r1;
}

// ---------------------------------------------------------------------------
// Kernel 4a: pack Wl2||Wr2 into bf16 MFMA B-fragment layout.
// ---------------------------------------------------------------------------
__global__ __launch_bounds__(256) void wprep_kernel(const float* __restrict__ Wl,
                                                    const float* __restrict__ Wr,
                                                    unsigned short* __restrict__ wbf) {
    const int t = blockIdx.x * 256 + threadIdx.x;   // 64*256 = 16384
    const int k = t >> 8;
    const int n = t & 255;
    const float v = (n < 128) ? Wl[k * 128 + n] : Wr[k * 128 + (n - 128)];
    wbf[((k >> 3) * 256 + n) * 8 + (k & 7)] = f2bf(v);
}

// ---------------------------------------------------------------------------
// Kernel 4b: lin2 via MFMA (mapping verified round 8). Outputs bf16.
// ---------------------------------------------------------------------------
__global__ __launch_bounds__(256) void lin2_kernel(const unsigned short* __restrict__ h1b,
                                                   const unsigned short* __restrict__ wbf,
                                                   const float* __restrict__ bl,
                                                   const float* __restrict__ br,
                                                   unsigned short* __restrict__ xl2b,
                                                   unsigned short* __restrict__ xr2b) {
    const int tid = threadIdx.x;
    const int lane = tid & 63;
    const int w = tid >> 6;
    const size_t node0 = (size_t)blockIdx.x * 16;
    const int lm = lane & 15, lk = lane >> 4;

    const short8* hp = (const short8*)h1b;
    const short8 a0 = hp[(node0 + lm) * 8 + lk];
    const short8 a1 = hp[(node0 + lm) * 8 + lk + 4];

    const short8* wp = (const short8*)wbf;
#pragma unroll
    for (int t = 0; t < 4; ++t) {
        const int col = w * 64 + t * 16 + lm;
        const float bias = (col < 128) ? bl[col] : br[col - 128];
        f4 acc = {bias, bias, bias, bias};
        const short8 b0 = wp[lk * 256 + col];
        const short8 b1 = wp[(lk + 4) * 256 + col];
        acc = __builtin_amdgcn_mfma_f32_16x16x32_bf16(a0, b0, acc, 0, 0, 0);
        acc = __builtin_amdgcn_mfma_f32_16x16x32_bf16(a1, b1, acc, 0, 0, 0);
        unsigned short* dst = (col < 128) ? (xl2b + col) : (xr2b + (col - 128));
#pragma unroll
        for (int r = 0; r < 4; ++r)
            dst[(node0 + lk * 4 + r) * 128] = f2bf(acc[r]);
    }
}

// ---------------------------------------------------------------------------
// Kernel 5: GATv2 layer-2 aggregation + pooling. bf16 gathers, XCD-swizzled.
// ---------------------------------------------------------------------------
__global__ __launch_bounds__(256) void agg2_pool_kernel(const unsigned short* __restrict__ xl2b,
                                                        const unsigned short* __restrict__ xr2b,
                                                        const int* __restrict__ knn,
                                                        const float* __restrict__ att,
                                                        float* __restrict__ partial) {
    const int x = blockIdx.x & 7;
    const int i = blockIdx.x >> 3;
    const int graph = x * 32 + (i >> 4);
    const int sub = i & 15;
    const int tid = threadIdx.x;
    const int lane = tid & 63;
    const int wv = tid >> 6;
    const int n8 = lane >> 3;
    const int h = (lane >> 1) & 3;
    const int half = lane & 1;
    const size_t node = (size_t)graph * NPG + sub * 32 + wv * 8 + n8;
    const int co = h * 32 + half * 16;

    const int* nb = knn + node * KNN;
    int j[KNN];
#pragma unroll
    for (int k = 0; k < KNN; ++k) j[k] = nb[k];

    f4 xr4[4], at4[4];
    {
        const short8* xrp = (const short8*)(xr2b + node * 128 + co);
        s8_to_f(xrp[0], &xr4[0]);
        s8_to_f(xrp[1], &xr4[2]);
        const f4* atp = (const f4*)(att + co);
#pragma unroll
        for (int i2 = 0; i2 < 4; ++i2) at4[i2] = atp[i2];
    }

    float alpha[KNN];
#pragma unroll
    for (int k = 0; k < KNN; ++k) {
        const short8* xlp = (const short8*)(xl2b + (size_t)j[k] * 128 + co);
        f4 xlv[4];
        s8_to_f(xlp[0], &xlv[0]);
        s8_to_f(xlp[1], &xlv[2]);
        float s = 0.f;
#pragma unroll
        for (int i2 = 0; i2 < 4; ++i2) {
            const f4 m = xlv[i2] + xr4[i2];
#pragma unroll
            for (int c = 0; c < 4; ++c) {
                float mm = m[c];
                mm = mm > 0.f ? mm : 0.2f * mm;
                s += mm * at4[i2][c];
            }
        }
        alpha[k] = s + __shfl_xor(s, 1);
    }
    float amax = alpha[0];
#pragma unroll
    for (int k = 1; k < KNN; ++k) amax = fmaxf(amax, alpha[k]);
    float e[KNN];
    float denom = 0.f;
#pragma unroll
    for (int k = 0; k < KNN; ++k) { e[k] = expf(alpha[k] - amax); denom += e[k]; }
    const float rd = 1.f / denom;

    f4 o4[4];
#pragma unroll
    for (int i2 = 0; i2 < 4; ++i2) o4[i2] = 0.f;
#pragma unroll
    for (int k = 0; k < KNN; ++k) {
        const short8* xlp = (const short8*)(xl2b + (size_t)j[k] * 128 + co);
        f4 xlv[4];
        s8_to_f(xlp[0], &xlv[0]);
        s8_to_f(xlp[1], &xlv[2]);
#pragma unroll
        for (int i2 = 0; i2 < 4; ++i2) o4[i2] += e[k] * xlv[i2];
    }
#pragma unroll
    for (int i2 = 0; i2 < 4; ++i2) o4[i2] *= rd;

#pragma unroll
    for (int m = 8; m <= 32; m <<= 1) {
#pragma unroll
        for (int i2 = 0; i2 < 4; ++i2) {
#pragma unroll
            for (int c = 0; c < 4; ++c) o4[i2][c] += __shfl_xor(o4[i2][c], m);
        }
    }
    if (n8 == 0) {
        f4* pp = (f4*)(partial + ((size_t)(graph * 16 + sub) * 4 + wv) * 128 + co);
#pragma unroll
        for (int i2 = 0; i2 < 4; ++i2) pp[i2] = o4[i2];
    }
}

// ---------------------------------------------------------------------------
// Kernel 6: stage-2 pool. One block per graph; 64 partials, /NPG, +bias2.
// ---------------------------------------------------------------------------
__global__ __launch_bounds__(128) void pool2_kernel(const float* __restrict__ partial,
                                                    const float* __restrict__ bias,
                                                    float* __restrict__ out) {
    const int g = blockIdx.x;
    const int c = threadIdx.x;
    float s = 0.f;
#pragma unroll
    for (int b = 0; b < 64; ++b) s += partial[(size_t)(g * 64 + b) * 128 + c];
    out[g * 128 + c] = s * (1.f / 512.f) + bias[c];
}

extern "C" void kernel_launch(void* const* d_in, const int* in_sizes, int n_in,
                              void* d_out, int out_size, void* d_ws, size_t ws_size,
                              hipStream_t stream) {
    const float* pos   = (const float*)d_in[0];
    const float* x     = (const float*)d_in[1];
    const float* Wl1   = (const float*)d_in[3];
    const float* bl1   = (const float*)d_in[4];
    const float* Wr1   = (const float*)d_in[5];
    const float* br1   = (const float*)d_in[6];
    const float* att1  = (const float*)d_in[7];
    const float* bias1 = (const float*)d_in[8];
    const float* Wl2   = (const float*)d_in[9];
    const float* bl2   = (const float*)d_in[10];
    const float* Wr2   = (const float*)d_in[11];
    const float* br2   = (const float*)d_in[12];
    const float* att2  = (const float*)d_in[13];
    const float* bias2 = (const float*)d_in[14];
    float* out = (float*)d_out;

    // Workspace layout (liveness-overlapped):
    //   [0,          3670016)  knn [N][7] i32                    (live: all)
    //   [3670016,   20447232)  xl1b bf16 [N][64]  (dead after agg1)
    //   [20447232,  37224448)  xr1  f32  [N][64]... (xr1 is f32: 33.5MB -> see below)
    //   xr1 f32 [N][64] = 33554432 B @ 20447232 -> ends 54001664
    //   h1b bf16 [N][64] @ 54001664 -> ends 70778880 (dead after lin2;
    //        partial [16384][128] f32 = 8.4MB overlays @ 54001664)
    //   wbf @ 70778880 (+32KB)
    //   xl2b bf16 [N][128] @ 88080384 -> ends 121634816
    //   xr2b bf16 [N][128] @ 121634816 -> ends 155189248
    char* ws = (char*)d_ws;
    int*            knn  = (int*)(ws + 0);
    unsigned short* xl1b = (unsigned short*)(ws + 3670016);
    float*          xr1  = (float*)(ws + 20447232);
    unsigned short* h1b  = (unsigned short*)(ws + 54001664);
    unsigned short* wbf  = (unsigned short*)(ws + 70778880);
    unsigned short* xl2b = (unsigned short*)(ws + 88080384);
    unsigned short* xr2b = (unsigned short*)(ws + 121634816);
    float*          partial = (float*)(ws + 54001664); // over dead h1b

    knn_kernel<<<B_GRAPHS * 2, 512, 0, stream>>>(pos, knn);
    lin1_kernel<<<(N_NODES * 16) / 256, 256, 0, stream>>>(x, Wl1, bl1, Wr1, br1, xl1b, xr1);
    wprep_kernel<<<64, 256, 0, stream>>>(Wl2, Wr2, wbf);
    agg1_kernel<<<(N_NODES * 4) / 256, 256, 0, stream>>>(xl1b, xr1, knn, att1, bias1, h1b);
    lin2_kernel<<<N_NODES / 16, 256, 0, stream>>>(h1b, wbf, bl2, br2, xl2b, xr2b);
    agg2_pool_kernel<<<N_NODES / 32, 256, 0, stream>>>(xl2b, xr2b, knn, att2, partial);
    pool2_kernel<<<B_GRAPHS, 128, 0, stream>>>(partial, bias2, out);
}

// Round 12
// 156.619 us; speedup vs baseline: 4.5325x; 1.0695x over previous
//
#include <hip/hip_runtime.h>
#include <hip/hip_bf16.h>

#define N_NODES 131072
#define B_GRAPHS 256
#define NPG 512
#define KNN 7
#define HEADS 4

using f4 = __attribute__((ext_vector_type(4))) float;
using short8 = __attribute__((ext_vector_type(8))) short;  // 8 bf16 (4 VGPRs)

__device__ __forceinline__ unsigned short f2bf(float f) {   // RNE f32->bf16
    unsigned u = __builtin_bit_cast(unsigned, f);
    u += 0x7FFFu + ((u >> 16) & 1u);
    return (unsigned short)(u >> 16);
}

__device__ __forceinline__ void s8_to_f(const short8 v, f4* out) {  // 8 bf16 -> 2 f4
#pragma unroll
    for (int i = 0; i < 8; ++i) {
        const unsigned u = ((unsigned)(unsigned short)v[i]) << 16;
        out[i >> 2][i & 3] = __builtin_bit_cast(float, u);
    }
}

__device__ __forceinline__ unsigned med3u(unsigned a, unsigned b, unsigned c) {
    unsigned r;
    asm("v_med3_u32 %0, %1, %2, %3" : "=v"(r) : "v"(a), "v"(b), "v"(c));
    return r;
}

// insert key into ascending top-7: valid because b[] is sorted, so
// max(b[i-1], min(b[i], k)) == med3(b[i-1], b[i], k). 1 umin + 6 med3 = 7 ops.
#define INS7(B, KEY) { \
    const unsigned _k = (KEY); \
    const unsigned n0 = min(B[0], _k); \
    const unsigned n1 = med3u(B[0], B[1], _k); \
    const unsigned n2 = med3u(B[1], B[2], _k); \
    const unsigned n3 = med3u(B[2], B[3], _k); \
    const unsigned n4 = med3u(B[3], B[4], _k); \
    const unsigned n5 = med3u(B[4], B[5], _k); \
    const unsigned n6 = med3u(B[5], B[6], _k); \
    B[0]=n0; B[1]=n1; B[2]=n2; B[3]=n3; B[4]=n4; B[5]=n5; B[6]=n6; }

// ---------------------------------------------------------------------------
// Kernel 1: kNN, 4-way candidate split. Block = 512 thr = 128 queries x 4
// candidate chunks of 128 (4 blocks/graph, 1024 blocks total -> 8 waves/SIMD;
// LDS 18.9KB x 4 blocks/CU = full 32-wave occupancy). Packed keys
// (bits(d2)&~0x1FF)|j, lower index wins ties (matches stable top_k).
// 3 partial lists merged through LDS (stride-7, conflict-free).
// ---------------------------------------------------------------------------
__global__ __launch_bounds__(512) void knn_kernel(const float* __restrict__ pos,
                                                  int* __restrict__ knn) {
    __shared__ f4 sp[NPG];
    __shared__ unsigned mk[3][128][7];
    const int tid = threadIdx.x;
    const int g = blockIdx.x >> 2;
    const int qh = blockIdx.x & 3;
    const int ch = tid >> 7;                 // candidate chunk 0..3
    const int ql = tid & 127;
    const int q = qh * 128 + ql;             // local query index

    const float* p = pos + (size_t)g * NPG * 3;
    {
        f4 v; v[0] = p[tid * 3 + 0]; v[1] = p[tid * 3 + 1]; v[2] = p[tid * 3 + 2]; v[3] = 0.f;
        sp[tid] = v;
    }
    __syncthreads();

    const f4 qp = sp[q];
    unsigned b[7];
#pragma unroll
    for (int i = 0; i < 7; ++i) b[i] = 0xFFFFFFFFu;

    const int j0 = ch << 7;
#pragma unroll 8
    for (int j = 0; j < 128; ++j) {
        const int jj = j0 + j;                  // wave-uniform
        const f4 c = sp[jj];                    // LDS broadcast
        const float dx = qp[0] - c[0];
        const float dy = qp[1] - c[1];
        const float dz = qp[2] - c[2];
        const float d2 = dx * dx + dy * dy + dz * dz;
        unsigned key = (__builtin_bit_cast(unsigned, d2) & 0xFFFFFE00u) | (unsigned)jj;
        key = (jj == q) ? 0xFFFFFFFFu : key;    // no self-loop
        INS7(b, key)
    }

    if (ch != 0) {
        unsigned* m = mk[ch - 1][ql];
#pragma unroll
        for (int i = 0; i < 7; ++i) m[i] = b[i];
    }
    __syncthreads();
    if (ch == 0) {
#pragma unroll
        for (int cc = 0; cc < 3; ++cc) {
            const unsigned* m = mk[cc][ql];
#pragma unroll
            for (int i = 0; i < 7; ++i) INS7(b, m[i])
        }
        const int base = (g * NPG + q) * KNN;
        const int off = g * NPG;
#pragma unroll
        for (int i = 0; i < 7; ++i) knn[base + i] = off + (int)(b[i] & 0x1FFu);
    }
}
#undef INS7

// ---------------------------------------------------------------------------
// Kernel 2: fused lin1. xl1 -> bf16 (gathered 14x by agg1), xr1 stays f32.
// ---------------------------------------------------------------------------
__global__ __launch_bounds__(256) void lin1_kernel(const float* __restrict__ x,
                                                   const float* __restrict__ Wl,
                                                   const float* __restrict__ bl,
                                                   const float* __restrict__ Wr,
                                                   const float* __restrict__ br,
                                                   unsigned short* __restrict__ xl1b,
                                                   float* __restrict__ xr1) {
    const int idx = blockIdx.x * 256 + threadIdx.x;   // N*16
    const int c4 = idx & 15;
    const size_t node = (size_t)(idx >> 4);
    const float* xrow = x + node * 10;
    f4 al = ((const f4*)bl)[c4];
    f4 ar = ((const f4*)br)[c4];
#pragma unroll
    for (int k = 0; k < 10; ++k) {
        const float xv = xrow[k];
        al += xv * ((const f4*)(Wl + k * 64))[c4];
        ar += xv * ((const f4*)(Wr + k * 64))[c4];
    }
    uint2 pk;
    pk.x = (unsigned)f2bf(al[0]) | ((unsigned)f2bf(al[1]) << 16);
    pk.y = (unsigned)f2bf(al[2]) | ((unsigned)f2bf(al[3]) << 16);
    ((uint2*)xl1b)[node * 16 + c4] = pk;
    ((f4*)(xr1 + node * 64))[c4] = ar;
}

// ---------------------------------------------------------------------------
// Kernel 3: GATv2 layer-1 aggregation. bf16 xl gathers, f32 xr/compute.
// XCD-swizzled. Writes h1 as bf16.
// ---------------------------------------------------------------------------
__global__ __launch_bounds__(256) void agg1_kernel(const unsigned short* __restrict__ xl1b,
                                                   const float* __restrict__ xr,
                                                   const int* __restrict__ knn,
                                                   const float* __restrict__ att,
                                                   const float* __restrict__ bias,
                                                   unsigned short* __restrict__ h1b) {
    const int x = blockIdx.x & 7;
    const int i = blockIdx.x >> 3;
    const int graph = x * 32 + (i >> 3);
    const int sub = i & 7;
    const int tid = threadIdx.x;
    const int h = tid & 3;
    const size_t node = (size_t)graph * NPG + sub * 64 + (tid >> 2);

    const int* nb = knn + node * KNN;
    int j[KNN];
#pragma unroll
    for (int k = 0; k < KNN; ++k) j[k] = nb[k];

    f4 xr4[4], at4[4];
    const f4* xrp = (const f4*)(xr + node * 64 + h * 16);
    const f4* atp = (const f4*)(att + h * 16);
#pragma unroll
    for (int i2 = 0; i2 < 4; ++i2) { xr4[i2] = xrp[i2]; at4[i2] = atp[i2]; }

    float alpha[KNN];
#pragma unroll
    for (int k = 0; k < KNN; ++k) {
        const short8* xlp = (const short8*)(xl1b + (size_t)j[k] * 64 + h * 16);
        f4 xlv[4];
        s8_to_f(xlp[0], &xlv[0]);
        s8_to_f(xlp[1], &xlv[2]);
        float s = 0.f;
#pragma unroll
        for (int i2 = 0; i2 < 4; ++i2) {
            const f4 m = xlv[i2] + xr4[i2];
#pragma unroll
            for (int c = 0; c < 4; ++c) {
                float mm = m[c];
                mm = mm > 0.f ? mm : 0.2f * mm;   // leaky_relu(., 0.2)
                s += mm * at4[i2][c];
            }
        }
        alpha[k] = s;
    }
    float amax = alpha[0];
#pragma unroll
    for (int k = 1; k < KNN; ++k) amax = fmaxf(amax, alpha[k]);
    float e[KNN];
    float denom = 0.f;
#pragma unroll
    for (int k = 0; k < KNN; ++k) { e[k] = expf(alpha[k] - amax); denom += e[k]; }
    const float rd = 1.f / denom;

    f4 o4[4];
#pragma unroll
    for (int i2 = 0; i2 < 4; ++i2) o4[i2] = 0.f;
#pragma unroll
    for (int k = 0; k < KNN; ++k) {
        const short8* xlp = (const short8*)(xl1b + (size_t)j[k] * 64 + h * 16);
        f4 xlv[4];
        s8_to_f(xlp[0], &xlv[0]);
        s8_to_f(xlp[1], &xlv[2]);
#pragma unroll
        for (int i2 = 0; i2 < 4; ++i2) o4[i2] += e[k] * xlv[i2];
    }
    const f4* bp = (const f4*)(bias + h * 16);
    short8 r0, r1;
#pragma unroll
    for (int i2 = 0; i2 < 4; ++i2) {
        const f4 v = o4[i2] * rd + bp[i2];
#pragma unroll
        for (int c = 0; c < 4; ++c) {
            const unsigned short bv = f2bf(v[c]);
            const int e4 = i2 * 4 + c;
            if (e4 < 8) r0[e4] = (short)bv; else r1[e4 - 8] = (short)bv;
        }
    }
    short8* hp = (short8*)(h1b + node * 64 + h * 16);
    hp[0] = r0;
    hp[1] = r1;
}

// ---------------------------------------------------------------------------
// Kernel 4a: pack Wl2||Wr2 into bf16 MFMA B-fragment layout.
// ---------------------------------------------------------------------------
__global__ __launch_bounds__(256) void wprep_kernel(const float* __restrict__ Wl,
                                                    const float* __restrict__ Wr,
                                                    unsigned short* __restrict__ wbf) {
    const int t = blockIdx.x * 256 + threadIdx.x;   // 64*256 = 16384
    const int k = t >> 8;
    const int n = t & 255;
    const float v = (n < 128) ? Wl[k * 128 + n] : Wr[k * 128 + (n - 128)];
    wbf[((k >> 3) * 256 + n) * 8 + (k & 7)] = f2bf(v);
}

// ---------------------------------------------------------------------------
// Kernel 4b: lin2 via MFMA (mapping verified round 8). Outputs bf16.
// ---------------------------------------------------------------------------
__global__ __launch_bounds__(256) void lin2_kernel(const unsigned short* __restrict__ h1b,
                                                   const unsigned short* __restrict__ wbf,
                                                   const float* __restrict__ bl,
                                                   const float* __restrict__ br,
                                                   unsigned short* __restrict__ xl2b,
                                                   unsigned short* __restrict__ xr2b) {
    const int tid = threadIdx.x;
    const int lane = tid & 63;
    const int w = tid >> 6;
    const size_t node0 = (size_t)blockIdx.x * 16;
    const int lm = lane & 15, lk = lane >> 4;

    const short8* hp = (const short8*)h1b;
    const short8 a0 = hp[(node0 + lm) * 8 + lk];
    const short8 a1 = hp[(node0 + lm) * 8 + lk + 4];

    const short8* wp = (const short8*)wbf;
#pragma unroll
    for (int t = 0; t < 4; ++t) {
        const int col = w * 64 + t * 16 + lm;
        const float bias = (col < 128) ? bl[col] : br[col - 128];
        f4 acc = {bias, bias, bias, bias};
        const short8 b0 = wp[lk * 256 + col];
        const short8 b1 = wp[(lk + 4) * 256 + col];
        acc = __builtin_amdgcn_mfma_f32_16x16x32_bf16(a0, b0, acc, 0, 0, 0);
        acc = __builtin_amdgcn_mfma_f32_16x16x32_bf16(a1, b1, acc, 0, 0, 0);
        unsigned short* dst = (col < 128) ? (xl2b + col) : (xr2b + (col - 128));
#pragma unroll
        for (int r = 0; r < 4; ++r)
            dst[(node0 + lk * 4 + r) * 128] = f2bf(acc[r]);
    }
}

// ---------------------------------------------------------------------------
// Kernel 5: GATv2 layer-2 aggregation + pooling. bf16 gathers, XCD-swizzled.
// ---------------------------------------------------------------------------
__global__ __launch_bounds__(256) void agg2_pool_kernel(const unsigned short* __restrict__ xl2b,
                                                        const unsigned short* __restrict__ xr2b,
                                                        const int* __restrict__ knn,
                                                        const float* __restrict__ att,
                                                        float* __restrict__ partial) {
    const int x = blockIdx.x & 7;
    const int i = blockIdx.x >> 3;
    const int graph = x * 32 + (i >> 4);
    const int sub = i & 15;
    const int tid = threadIdx.x;
    const int lane = tid & 63;
    const int wv = tid >> 6;
    const int n8 = lane >> 3;
    const int h = (lane >> 1) & 3;
    const int half = lane & 1;
    const size_t node = (size_t)graph * NPG + sub * 32 + wv * 8 + n8;
    const int co = h * 32 + half * 16;

    const int* nb = knn + node * KNN;
    int j[KNN];
#pragma unroll
    for (int k = 0; k < KNN; ++k) j[k] = nb[k];

    f4 xr4[4], at4[4];
    {
        const short8* xrp = (const short8*)(xr2b + node * 128 + co);
        s8_to_f(xrp[0], &xr4[0]);
        s8_to_f(xrp[1], &xr4[2]);
        const f4* atp = (const f4*)(att + co);
#pragma unroll
        for (int i2 = 0; i2 < 4; ++i2) at4[i2] = atp[i2];
    }

    float alpha[KNN];
#pragma unroll
    for (int k = 0; k < KNN; ++k) {
        const short8* xlp = (const short8*)(xl2b + (size_t)j[k] * 128 + co);
        f4 xlv[4];
        s8_to_f(xlp[0], &xlv[0]);
        s8_to_f(xlp[1], &xlv[2]);
        float s = 0.f;
#pragma unroll
        for (int i2 = 0; i2 < 4; ++i2) {
            const f4 m = xlv[i2] + xr4[i2];
#pragma unroll
            for (int c = 0; c < 4; ++c) {
                float mm = m[c];
                mm = mm > 0.f ? mm : 0.2f * mm;
                s += mm * at4[i2][c];
            }
        }
        alpha[k] = s + __shfl_xor(s, 1);
    }
    float amax = alpha[0];
#pragma unroll
    for (int k = 1; k < KNN; ++k) amax = fmaxf(amax, alpha[k]);
    float e[KNN];
    float denom = 0.f;
#pragma unroll
    for (int k = 0; k < KNN; ++k) { e[k] = expf(alpha[k] - amax); denom += e[k]; }
    const float rd = 1.f / denom;

    f4 o4[4];
#pragma unroll
    for (int i2 = 0; i2 < 4; ++i2) o4[i2] = 0.f;
#pragma unroll
    for (int k = 0; k < KNN; ++k) {
        const short8* xlp = (const short8*)(xl2b + (size_t)j[k] * 128 + co);
        f4 xlv[4];
        s8_to_f(xlp[0], &xlv[0]);
        s8_to_f(xlp[1], &xlv[2]);
#pragma unroll
        for (int i2 = 0; i2 < 4; ++i2) o4[i2] += e[k] * xlv[i2];
    }
#pragma unroll
    for (int i2 = 0; i2 < 4; ++i2) o4[i2] *= rd;

#pragma unroll
    for (int m = 8; m <= 32; m <<= 1) {
#pragma unroll
        for (int i2 = 0; i2 < 4; ++i2) {
#pragma unroll
            for (int c = 0; c < 4; ++c) o4[i2][c] += __shfl_xor(o4[i2][c], m);
        }
    }
    if (n8 == 0) {
        f4* pp = (f4*)(partial + ((size_t)(graph * 16 + sub) * 4 + wv) * 128 + co);
#pragma unroll
        for (int i2 = 0; i2 < 4; ++i2) pp[i2] = o4[i2];
    }
}

// ---------------------------------------------------------------------------
// Kernel 6: stage-2 pool. One block per graph; 64 partials, /NPG, +bias2.
// ---------------------------------------------------------------------------
__global__ __launch_bounds__(128) void pool2_kernel(const float* __restrict__ partial,
                                                    const float* __restrict__ bias,
                                                    float* __restrict__ out) {
    const int g = blockIdx.x;
    const int c = threadIdx.x;
    float s = 0.f;
#pragma unroll
    for (int b = 0; b < 64; ++b) s += partial[(size_t)(g * 64 + b) * 128 + c];
    out[g * 128 + c] = s * (1.f / 512.f) + bias[c];
}

extern "C" void kernel_launch(void* const* d_in, const int* in_sizes, int n_in,
                              void* d_out, int out_size, void* d_ws, size_t ws_size,
                              hipStream_t stream) {
    const float* pos   = (const float*)d_in[0];
    const float* x     = (const float*)d_in[1];
    const float* Wl1   = (const float*)d_in[3];
    const float* bl1   = (const float*)d_in[4];
    const float* Wr1   = (const float*)d_in[5];
    const float* br1   = (const float*)d_in[6];
    const float* att1  = (const float*)d_in[7];
    const float* bias1 = (const float*)d_in[8];
    const float* Wl2   = (const float*)d_in[9];
    const float* bl2   = (const float*)d_in[10];
    const float* Wr2   = (const float*)d_in[11];
    const float* br2   = (const float*)d_in[12];
    const float* att2  = (const float*)d_in[13];
    const float* bias2 = (const float*)d_in[14];
    float* out = (float*)d_out;

    // Workspace layout (liveness-overlapped):
    //   [0,          3670016)  knn [N][7] i32                    (live: all)
    //   [3670016,   20447232)  xl1b bf16 [N][64]  (dead after agg1)
    //   [20447232,  54001664)  xr1  f32  [N][64]  (dead after agg1)
    //   [54001664,  70778880)  h1b bf16 [N][64]   (dead after lin2;
    //        partial [16384][128] f32 = 8.4MB overlays here)
    //   [70778880,  70811648)  wbf bf16 32KB
    //   [88080384, 121634816)  xl2b bf16 [N][128]
    //   [121634816,155189248)  xr2b bf16 [N][128]
    char* ws = (char*)d_ws;
    int*            knn  = (int*)(ws + 0);
    unsigned short* xl1b = (unsigned short*)(ws + 3670016);
    float*          xr1  = (float*)(ws + 20447232);
    unsigned short* h1b  = (unsigned short*)(ws + 54001664);
    unsigned short* wbf  = (unsigned short*)(ws + 70778880);
    unsigned short* xl2b = (unsigned short*)(ws + 88080384);
    unsigned short* xr2b = (unsigned short*)(ws + 121634816);
    float*          partial = (float*)(ws + 54001664); // over dead h1b

    knn_kernel<<<B_GRAPHS * 4, 512, 0, stream>>>(pos, knn);
    lin1_kernel<<<(N_NODES * 16) / 256, 256, 0, stream>>>(x, Wl1, bl1, Wr1, br1, xl1b, xr1);
    wprep_kernel<<<64, 256, 0, stream>>>(Wl2, Wr2, wbf);
    agg1_kernel<<<(N_NODES * 4) / 256, 256, 0, stream>>>(xl1b, xr1, knn, att1, bias1, h1b);
    lin2_kernel<<<N_NODES / 16, 256, 0, stream>>>(h1b, wbf, bl2, br2, xl2b, xr2b);
    agg2_pool_kernel<<<N_NODES / 32, 256, 0, stream>>>(xl2b, xr2b, knn, att2, partial);
    pool2_kernel<<<B_GRAPHS, 128, 0, stream>>>(partial, bias2, out);
}